// Round 1
// baseline (2411.837 us; speedup 1.0000x reference)
//
#include <hip/hip_runtime.h>
#include <cstddef>

#define NN 50000      // nodes
#define EE 800000     // edges per adjacency
#define KF 500        // NFEAT
#define D1 128        // H2
#define D2 64         // H3
#define D3 64         // H4
#define NC 7          // classes
#define NI 5000       // index size

// ---------------- CSR build ----------------
__global__ void hist_kernel(const int* __restrict__ r, int* __restrict__ cnt, int n){
  int i = blockIdx.x*blockDim.x + threadIdx.x;
  if (i < n) atomicAdd(&cnt[r[i]], 1);
}

__global__ __launch_bounds__(1024) void scan_kernel(const int* __restrict__ cnt, int* __restrict__ row_ptr,
                                                    int* __restrict__ fill, int n){
  __shared__ int buf[1024];
  __shared__ int carry;
  int tid = threadIdx.x;
  if (tid == 0) carry = 0;
  __syncthreads();
  for (int base = 0; base < n; base += 1024){
    int i = base + tid;
    int v = (i < n) ? cnt[i] : 0;
    buf[tid] = v;
    __syncthreads();
    for (int off = 1; off < 1024; off <<= 1){
      int t = (tid >= off) ? buf[tid - off] : 0;
      __syncthreads();
      if (tid >= off) buf[tid] += t;
      __syncthreads();
    }
    int excl = carry + buf[tid] - v;
    if (i < n){ row_ptr[i] = excl; fill[i] = excl; }
    __syncthreads();
    if (tid == 0) carry += buf[1023];
    __syncthreads();
  }
  if (tid == 0) row_ptr[n] = carry;
}

__global__ void scatter_kernel(const int* __restrict__ r, const int* __restrict__ c, const float* __restrict__ v,
                               int* __restrict__ fill, int* __restrict__ cc, float* __restrict__ cv, int n){
  int i = blockIdx.x*blockDim.x + threadIdx.x;
  if (i < n){
    int p = atomicAdd(&fill[r[i]], 1);
    cc[p] = c[i];
    cv[p] = v[i];
  }
}

// ---------------- fp32 tiled GEMM: C[M,N] = A[M,K] @ B[K,N] ----------------
__global__ __launch_bounds__(256) void gemm_kernel(const float* __restrict__ A, const float* __restrict__ B,
                                                   float* __restrict__ C, int M, int N, int K){
  __shared__ __align__(16) float As[16][68];
  __shared__ __align__(16) float Bs[16][68];
  int tid = threadIdx.x;
  int tx = tid & 15, ty = tid >> 4;
  int row0 = blockIdx.y*64, col0 = blockIdx.x*64;
  float acc[4][4] = {};
  for (int k0 = 0; k0 < K; k0 += 16){
    // load A tile 64x16
    for (int l = tid; l < 64*16; l += 256){
      int i = l >> 4, j = l & 15;
      int gr = row0 + i, gk = k0 + j;
      As[j][i] = (gr < M && gk < K) ? A[(size_t)gr*K + gk] : 0.f;
    }
    // load B tile 16x64
    for (int l = tid; l < 16*64; l += 256){
      int kk = l >> 6, n = l & 63;
      int gk = k0 + kk, gc = col0 + n;
      Bs[kk][n] = (gk < K && gc < N) ? B[(size_t)gk*N + gc] : 0.f;
    }
    __syncthreads();
    #pragma unroll
    for (int kk = 0; kk < 16; ++kk){
      float4 av = *reinterpret_cast<const float4*>(&As[kk][ty*4]);
      float4 bv = *reinterpret_cast<const float4*>(&Bs[kk][tx*4]);
      float a4[4] = {av.x, av.y, av.z, av.w};
      float b4[4] = {bv.x, bv.y, bv.z, bv.w};
      #pragma unroll
      for (int m = 0; m < 4; ++m)
        #pragma unroll
        for (int n = 0; n < 4; ++n)
          acc[m][n] += a4[m]*b4[n];
    }
    __syncthreads();
  }
  #pragma unroll
  for (int m = 0; m < 4; ++m){
    int gr = row0 + ty*4 + m;
    if (gr < M){
      #pragma unroll
      for (int n = 0; n < 4; ++n){
        int gc = col0 + tx*4 + n;
        if (gc < N) C[(size_t)gr*N + gc] = acc[m][n];
      }
    }
  }
}

// ---------------- gather SpMM: out[row] = sum_e cv*S[cc] (+bias, relu) ----------------
template<int H, int RELU>
__global__ __launch_bounds__(256) void spmm_kernel(const int* __restrict__ row_ptr, const int* __restrict__ cc,
                                                   const float* __restrict__ cv, const float* __restrict__ S,
                                                   const float* __restrict__ bias, float* __restrict__ out){
  int row = blockIdx.x*4 + (threadIdx.x >> 6);
  int lane = threadIdx.x & 63;
  if (row >= NN) return;
  int p0 = row_ptr[row], p1 = row_ptr[row+1];
  if (H == 128){
    float2 acc = make_float2(0.f, 0.f);
    for (int p = p0; p < p1; ++p){
      int c = cc[p]; float v = cv[p];
      float2 s = ((const float2*)(S + (size_t)c*128))[lane];
      acc.x += v*s.x; acc.y += v*s.y;
    }
    float2 b = ((const float2*)bias)[lane];
    acc.x += b.x; acc.y += b.y;
    if (RELU){ acc.x = fmaxf(acc.x, 0.f); acc.y = fmaxf(acc.y, 0.f); }
    ((float2*)(out + (size_t)row*128))[lane] = acc;
  } else {
    float acc = 0.f;
    for (int p = p0; p < p1; ++p){
      acc += cv[p] * S[(size_t)cc[p]*64 + lane];
    }
    acc += bias[lane];
    if (RELU) acc = fmaxf(acc, 0.f);
    out[(size_t)row*64 + lane] = acc;
  }
}

// ---------------- tall-skinny dense: out[M,7] = (relu?)([A1|A2]) @ W + b ----------------
__global__ __launch_bounds__(256) void dense7_kernel(const float* __restrict__ A1, const float* __restrict__ A2,
                                                     int K1, int K2, const float* __restrict__ W,
                                                     const float* __restrict__ bias, float* __restrict__ out,
                                                     int M, int relu_in){
  __shared__ float Ws[128*NC];
  __shared__ float bs[NC];
  int K = K1 + K2;
  for (int i = threadIdx.x; i < K*NC; i += 256) Ws[i] = W[i];
  if (threadIdx.x < NC) bs[threadIdx.x] = bias[threadIdx.x];
  __syncthreads();
  int row = blockIdx.x*256 + threadIdx.x;
  if (row >= M) return;
  float acc[NC];
  #pragma unroll
  for (int n = 0; n < NC; ++n) acc[n] = bs[n];
  const float* a = A1 + (size_t)row*K1;
  for (int k = 0; k < K1; ++k){
    float av = a[k];
    if (relu_in) av = fmaxf(av, 0.f);
    #pragma unroll
    for (int n = 0; n < NC; ++n) acc[n] += av*Ws[k*NC + n];
  }
  if (A2){
    const float* a2 = A2 + (size_t)row*K2;
    for (int k = 0; k < K2; ++k){
      float av = a2[k];
      if (relu_in) av = fmaxf(av, 0.f);
      #pragma unroll
      for (int n = 0; n < NC; ++n) acc[n] += av*Ws[(K1 + k)*NC + n];
    }
  }
  #pragma unroll
  for (int n = 0; n < NC; ++n) out[(size_t)row*NC + n] = acc[n];
}

// ---------------- alpha reduction ----------------
__global__ __launch_bounds__(1024) void alpha_kernel(const float* __restrict__ base, const float* __restrict__ gate,
                                                     const float* __restrict__ y, const int* __restrict__ index,
                                                     float* __restrict__ alpha_out){
  __shared__ float r1[1024], r2[1024];
  int tid = threadIdx.x;
  float s1 = 0.f, sall = 0.f;
  for (int i = tid; i < NI*NC; i += 1024){
    int ii = i / NC, n = i - ii*NC;
    int r = index[ii];
    float yv = y[(size_t)r*NC + n];
    float b = base[(size_t)r*NC + n];
    float g = gate[(size_t)r*NC + n];
    float te = expf(-b*yv);
    sall += te;
    if (g*yv >= 0.f) s1 += te;
  }
  r1[tid] = s1; r2[tid] = sall;
  __syncthreads();
  for (int off = 512; off > 0; off >>= 1){
    if (tid < off){ r1[tid] += r1[tid+off]; r2[tid] += r2[tid+off]; }
    __syncthreads();
  }
  if (tid == 0){
    float s2 = r2[0] - r1[0];
    alpha_out[0] = 0.5f*logf(s2/r1[0]);
  }
}

__global__ void axpy_kernel(const float* __restrict__ a, const float* __restrict__ b,
                            const float* __restrict__ alpha, float* __restrict__ out, int n){
  int i = blockIdx.x*blockDim.x + threadIdx.x;
  if (i < n) out[i] = a[i] + alpha[0]*b[i];
}

// ---------------- host ----------------
extern "C" void kernel_launch(void* const* d_in, const int* in_sizes, int n_in,
                              void* d_out, int out_size, void* d_ws, size_t ws_size,
                              hipStream_t stream){
  const float* x     = (const float*)d_in[0];
  const float* y     = (const float*)d_in[1];
  const int*   index = (const int*)d_in[2];
  const int*   a1r = (const int*)d_in[3];  const int* a1c = (const int*)d_in[4];  const float* a1v = (const float*)d_in[5];
  const int*   a3r = (const int*)d_in[9];  const int* a3c = (const int*)d_in[10]; const float* a3v = (const float*)d_in[11];
  const int*   a4r = (const int*)d_in[12]; const int* a4c = (const int*)d_in[13]; const float* a4v = (const float*)d_in[14];
  const int*   a5r = (const int*)d_in[15]; const int* a5c = (const int*)d_in[16]; const float* a5v = (const float*)d_in[17];
  const float* w1  = (const float*)d_in[18]; const float* b1  = (const float*)d_in[19];
  const float* w2  = (const float*)d_in[20]; const float* b2  = (const float*)d_in[21];
  const float* w3  = (const float*)d_in[22]; const float* b3  = (const float*)d_in[23];
  const float* w4  = (const float*)d_in[24]; const float* b4  = (const float*)d_in[25];
  const float* w5  = (const float*)d_in[26]; const float* b5  = (const float*)d_in[27];
  const float* w6  = (const float*)d_in[28]; const float* b6  = (const float*)d_in[29];
  const float* w10 = (const float*)d_in[30]; const float* b10 = (const float*)d_in[31];
  const float* w11 = (const float*)d_in[32]; const float* b11 = (const float*)d_in[33];
  const float* w12 = (const float*)d_in[34]; const float* b12 = (const float*)d_in[35];
  const float* d1w = (const float*)d_in[36]; const float* d1b = (const float*)d_in[37];
  const float* d2w = (const float*)d_in[38]; const float* d2b = (const float*)d_in[39];
  const float* d3w = (const float*)d_in[40]; const float* d3b = (const float*)d_in[41];
  const float* d4w = (const float*)d_in[42]; const float* d4b = (const float*)d_in[43];
  const float* sw  = (const float*)d_in[44]; const float* sb  = (const float*)d_in[45];
  float* out = (float*)d_out;

  // ---- carve workspace ----
  char* p = (char*)d_ws;
  auto carve = [&](size_t bytes) -> char* {
    char* q = p;
    p += (bytes + 255) & ~size_t(255);
    return q;
  };
  float* S    = (float*)carve((size_t)NN*D1*4);   // layer-1 support (kept across x2/x3)
  float* SB   = (float*)carve((size_t)NN*D2*4);   // layer-2/3 support
  float* H1b  = (float*)carve((size_t)NN*D1*4);
  float* H2b  = (float*)carve((size_t)NN*D2*4);
  float* XB   = (float*)carve((size_t)NN*D3*4);   // x1 / x4 raw
  float* X2   = (float*)carve((size_t)NN*D3*4);
  float* X3   = (float*)carve((size_t)NN*D3*4);
  float* X1D  = (float*)carve((size_t)NN*NC*4);
  float* X4D  = (float*)carve((size_t)NN*NC*4);
  float* SIM  = (float*)carve((size_t)NN*NC*4);
  float* ALPHA= (float*)carve(256);
  int*   ROWP = (int*)carve((size_t)(NN+1)*4);
  int*   FILL = (int*)carve((size_t)NN*4);
  int*   CNT  = (int*)carve((size_t)NN*4);
  int*   CC   = (int*)carve((size_t)EE*4);
  float* CV   = (float*)carve((size_t)EE*4);
  (void)ws_size; (void)n_in; (void)in_sizes; (void)out_size;

  float* OUT_X2D = out;                 // 350000
  float* OUT_X3D = out + (size_t)NN*NC; // 350000
  float* OUT_P2  = out + (size_t)2*NN*NC;

  auto build_csr = [&](const int* r, const int* c, const float* v){
    hipMemsetAsync(CNT, 0, (size_t)NN*4, stream);
    hist_kernel<<<(EE+255)/256, 256, 0, stream>>>(r, CNT, EE);
    scan_kernel<<<1, 1024, 0, stream>>>(CNT, ROWP, FILL, NN);
    scatter_kernel<<<(EE+255)/256, 256, 0, stream>>>(r, c, v, FILL, CC, CV, EE);
  };
  auto gemm = [&](const float* A, const float* B, float* C, int M, int N, int K){
    dim3 g((N+63)/64, (M+63)/64);
    gemm_kernel<<<g, 256, 0, stream>>>(A, B, C, M, N, K);
  };

  auto run_branch = [&](const int* ar, const int* ac, const float* av,
                        const float* Wa, const float* ba, const float* Wb, const float* bb,
                        const float* Wc, const float* bc,
                        const float* dW, const float* db,
                        float* xout, float* dout, bool compute_S){
    build_csr(ar, ac, av);
    if (compute_S) gemm(x, Wa, S, NN, D1, KF);
    spmm_kernel<128,1><<<(NN+3)/4, 256, 0, stream>>>(ROWP, CC, CV, S, ba, H1b);
    gemm(H1b, Wb, SB, NN, D2, D1);
    spmm_kernel<64,1><<<(NN+3)/4, 256, 0, stream>>>(ROWP, CC, CV, SB, bb, H2b);
    gemm(H2b, Wc, SB, NN, D3, D2);
    spmm_kernel<64,0><<<(NN+3)/4, 256, 0, stream>>>(ROWP, CC, CV, SB, bc, xout);
    dense7_kernel<<<(NN+255)/256, 256, 0, stream>>>(xout, nullptr, D3, 0, dW, db, dout, NN, 1);
  };

  // x1: adjacency a5, weights w1-w3, proj d1 -> X1D
  run_branch(a5r, a5c, a5v, w1, b1, w2, b2, w3, b3, d1w, d1b, XB, X1D, true);
  // x2: adjacency a4, weights w4-w6, proj d2 -> out[0]
  run_branch(a4r, a4c, a4v, w4, b4, w5, b5, w6, b6, d2w, d2b, X2, OUT_X2D, true);
  // x3: adjacency a3, SAME weights w4-w6 (S = x@w4 still valid!), proj d3 -> out[1]
  run_branch(a3r, a3c, a3v, w4, b4, w5, b5, w6, b6, d3w, d3b, X3, OUT_X3D, false);
  // x4: adjacency a1, weights w10-w12, proj d4 -> X4D
  run_branch(a1r, a1c, a1v, w10, b10, w11, b11, w12, b12, d4w, d4b, XB, X4D, true);

  // sim = [x2 | x3] @ sw + sb
  dense7_kernel<<<(NN+255)/256, 256, 0, stream>>>(X2, X3, D3, D3, sw, sb, SIM, NN, 0);

  // part1 = x4d + alpha(x4d, sim)*sim   (into OUT_P2)
  alpha_kernel<<<1, 1024, 0, stream>>>(X4D, SIM, y, index, ALPHA);
  axpy_kernel<<<((NN*NC)+255)/256, 256, 0, stream>>>(X4D, SIM, ALPHA, OUT_P2, NN*NC);
  // part2 = part1 + alpha(part1, x1d)*x1d  (in place)
  alpha_kernel<<<1, 1024, 0, stream>>>(OUT_P2, X1D, y, index, ALPHA+1);
  axpy_kernel<<<((NN*NC)+255)/256, 256, 0, stream>>>(OUT_P2, X1D, ALPHA+1, OUT_P2, NN*NC);
}

// Round 2
// 2003.922 us; speedup vs baseline: 1.2036x; 1.2036x over previous
//
#include <hip/hip_runtime.h>
#include <cstddef>

#define NN 50000      // nodes
#define EE 800000     // edges per adjacency
#define KF 500        // NFEAT
#define D1 128        // H2
#define D2 64         // H3
#define D3 64         // H4
#define NC 7          // classes
#define NI 5000       // index size

// ---------------- CSR build ----------------
__global__ void hist_kernel(const int* __restrict__ r, int* __restrict__ cnt, int n){
  int i = blockIdx.x*blockDim.x + threadIdx.x;
  if (i < n) atomicAdd(&cnt[r[i]], 1);
}

// parallel 3-stage scan: (1) per-block exclusive scan + block sums
__global__ __launch_bounds__(256) void scan1_kernel(const int* __restrict__ cnt, int* __restrict__ chunk,
                                                    int* __restrict__ bsum, int n){
  __shared__ int buf[256];
  int tid = threadIdx.x;
  int i = blockIdx.x*256 + tid;
  int v = (i < n) ? cnt[i] : 0;
  buf[tid] = v;
  __syncthreads();
  for (int off = 1; off < 256; off <<= 1){
    int t = (tid >= off) ? buf[tid - off] : 0;
    __syncthreads();
    buf[tid] += t;
    __syncthreads();
  }
  if (i < n) chunk[i] = buf[tid] - v;          // exclusive within block
  if (tid == 255) bsum[blockIdx.x] = buf[255]; // block total
}
// (2) single-block exclusive scan of block sums (nb <= 256)
__global__ __launch_bounds__(256) void scan2_kernel(int* __restrict__ bsum, int nb){
  __shared__ int buf[256];
  int tid = threadIdx.x;
  int v = (tid < nb) ? bsum[tid] : 0;
  buf[tid] = v;
  __syncthreads();
  for (int off = 1; off < 256; off <<= 1){
    int t = (tid >= off) ? buf[tid - off] : 0;
    __syncthreads();
    buf[tid] += t;
    __syncthreads();
  }
  if (tid < nb) bsum[tid] = buf[tid] - v;      // exclusive
}
// (3) add block offsets -> row_ptr & fill
__global__ void scan3_kernel(const int* __restrict__ chunk, const int* __restrict__ bsum,
                             int* __restrict__ row_ptr, int* __restrict__ fill, int n, int total){
  int i = blockIdx.x*256 + threadIdx.x;
  if (i < n){
    int e = chunk[i] + bsum[blockIdx.x];
    row_ptr[i] = e; fill[i] = e;
  }
  if (i == 0) row_ptr[n] = total;
}

__global__ void scatter_kernel(const int* __restrict__ r, const int* __restrict__ c, const float* __restrict__ v,
                               int* __restrict__ fill, int* __restrict__ cc, float* __restrict__ cv, int n){
  int i = blockIdx.x*blockDim.x + threadIdx.x;
  if (i < n){
    int p = atomicAdd(&fill[r[i]], 1);
    cc[p] = c[i];
    cv[p] = v[i];
  }
}

// ---------------- fast fp32 GEMM, N fixed = 128: C[M,128] = A[M,K] @ B[K,128] ----------------
__global__ __launch_bounds__(256) void gemm_fast_kernel(const float* __restrict__ A, const float* __restrict__ B,
                                                        float* __restrict__ C, int M, int K){
  __shared__ __align__(16) float As[16][132];
  __shared__ __align__(16) float Bs[16][132];
  int tid = threadIdx.x;
  int tx = tid & 15, ty = tid >> 4;
  int row0 = blockIdx.x*128;
  float acc[8][8] = {};
  int ar = tid >> 2, akq = tid & 3;
  for (int k0 = 0; k0 < K; k0 += 16){
    // A tile 128x16 -> transposed As[k][m]
    #pragma unroll
    for (int h = 0; h < 2; ++h){
      int r = ar + h*64;
      int gr = row0 + r;
      int gk = k0 + akq*4;
      float4 av = make_float4(0.f,0.f,0.f,0.f);
      if (gr < M){
        if (gk + 4 <= K) av = *reinterpret_cast<const float4*>(&A[(size_t)gr*K + gk]);
        else {
          float t0 = (gk   < K) ? A[(size_t)gr*K + gk  ] : 0.f;
          float t1 = (gk+1 < K) ? A[(size_t)gr*K + gk+1] : 0.f;
          float t2 = (gk+2 < K) ? A[(size_t)gr*K + gk+2] : 0.f;
          float t3 = (gk+3 < K) ? A[(size_t)gr*K + gk+3] : 0.f;
          av = make_float4(t0,t1,t2,t3);
        }
      }
      As[akq*4+0][r] = av.x; As[akq*4+1][r] = av.y;
      As[akq*4+2][r] = av.z; As[akq*4+3][r] = av.w;
    }
    // B tile 16x128
    {
      int n = (tid & 31)*4;
      #pragma unroll
      for (int kb = tid >> 5; kb < 16; kb += 8){
        int gk = k0 + kb;
        float4 bv = make_float4(0.f,0.f,0.f,0.f);
        if (gk < K) bv = *reinterpret_cast<const float4*>(&B[(size_t)gk*128 + n]);
        *reinterpret_cast<float4*>(&Bs[kb][n]) = bv;
      }
    }
    __syncthreads();
    #pragma unroll
    for (int kk = 0; kk < 16; ++kk){
      float a[8], b[8];
      *(float4*)&a[0] = *(const float4*)&As[kk][ty*4];
      *(float4*)&a[4] = *(const float4*)&As[kk][64 + ty*4];
      *(float4*)&b[0] = *(const float4*)&Bs[kk][tx*4];
      *(float4*)&b[4] = *(const float4*)&Bs[kk][64 + tx*4];
      #pragma unroll
      for (int m = 0; m < 8; ++m)
        #pragma unroll
        for (int n2 = 0; n2 < 8; ++n2)
          acc[m][n2] += a[m]*b[n2];
    }
    __syncthreads();
  }
  #pragma unroll
  for (int m = 0; m < 8; ++m){
    int r = (m < 4) ? (ty*4 + m) : (64 + ty*4 + (m-4));
    int gr = row0 + r;
    if (gr >= M) continue;
    *reinterpret_cast<float4*>(&C[(size_t)gr*128 + tx*4])      = *(float4*)&acc[m][0];
    *reinterpret_cast<float4*>(&C[(size_t)gr*128 + 64 + tx*4]) = *(float4*)&acc[m][4];
  }
}

// ---------------- generic fp32 tiled GEMM (64x64 tile) for small N ----------------
__global__ __launch_bounds__(256) void gemm_kernel(const float* __restrict__ A, const float* __restrict__ B,
                                                   float* __restrict__ C, int M, int N, int K){
  __shared__ __align__(16) float As[16][68];
  __shared__ __align__(16) float Bs[16][68];
  int tid = threadIdx.x;
  int tx = tid & 15, ty = tid >> 4;
  int row0 = blockIdx.y*64, col0 = blockIdx.x*64;
  float acc[4][4] = {};
  for (int k0 = 0; k0 < K; k0 += 16){
    for (int l = tid; l < 64*16; l += 256){
      int i = l >> 4, j = l & 15;
      int gr = row0 + i, gk = k0 + j;
      As[j][i] = (gr < M && gk < K) ? A[(size_t)gr*K + gk] : 0.f;
    }
    for (int l = tid; l < 16*64; l += 256){
      int kk = l >> 6, n = l & 63;
      int gk = k0 + kk, gc = col0 + n;
      Bs[kk][n] = (gk < K && gc < N) ? B[(size_t)gk*N + gc] : 0.f;
    }
    __syncthreads();
    #pragma unroll
    for (int kk = 0; kk < 16; ++kk){
      float4 av = *reinterpret_cast<const float4*>(&As[kk][ty*4]);
      float4 bv = *reinterpret_cast<const float4*>(&Bs[kk][tx*4]);
      float a4[4] = {av.x, av.y, av.z, av.w};
      float b4[4] = {bv.x, bv.y, bv.z, bv.w};
      #pragma unroll
      for (int m = 0; m < 4; ++m)
        #pragma unroll
        for (int n = 0; n < 4; ++n)
          acc[m][n] += a4[m]*b4[n];
    }
    __syncthreads();
  }
  #pragma unroll
  for (int m = 0; m < 4; ++m){
    int gr = row0 + ty*4 + m;
    if (gr < M){
      #pragma unroll
      for (int n = 0; n < 4; ++n){
        int gc = col0 + tx*4 + n;
        if (gc < N) C[(size_t)gr*N + gc] = acc[m][n];
      }
    }
  }
}

// ---------------- gather SpMM: out[row] = sum_e cv*S[cc] (+bias, relu) ----------------
template<int H, int RELU>
__global__ __launch_bounds__(256) void spmm_kernel(const int* __restrict__ row_ptr, const int* __restrict__ cc,
                                                   const float* __restrict__ cv, const float* __restrict__ S,
                                                   const float* __restrict__ bias, float* __restrict__ out){
  int row = blockIdx.x*4 + (threadIdx.x >> 6);
  int lane = threadIdx.x & 63;
  if (row >= NN) return;
  int p0 = row_ptr[row], p1 = row_ptr[row+1];
  if (H == 128){
    float2 acc = make_float2(0.f, 0.f);
    for (int p = p0; p < p1; ++p){
      int c = cc[p]; float v = cv[p];
      float2 s = ((const float2*)(S + (size_t)c*128))[lane];
      acc.x += v*s.x; acc.y += v*s.y;
    }
    float2 b = ((const float2*)bias)[lane];
    acc.x += b.x; acc.y += b.y;
    if (RELU){ acc.x = fmaxf(acc.x, 0.f); acc.y = fmaxf(acc.y, 0.f); }
    ((float2*)(out + (size_t)row*128))[lane] = acc;
  } else {
    float acc = 0.f;
    for (int p = p0; p < p1; ++p){
      acc += cv[p] * S[(size_t)cc[p]*64 + lane];
    }
    acc += bias[lane];
    if (RELU) acc = fmaxf(acc, 0.f);
    out[(size_t)row*64 + lane] = acc;
  }
}

// ---------------- tall-skinny dense: out[M,7] = (relu?)([A1|A2]) @ W + b ----------------
__global__ __launch_bounds__(256) void dense7_kernel(const float* __restrict__ A1, const float* __restrict__ A2,
                                                     int K1, int K2, const float* __restrict__ W,
                                                     const float* __restrict__ bias, float* __restrict__ out,
                                                     int M, int relu_in){
  __shared__ float Ws[128*NC];
  __shared__ float bs[NC];
  int K = K1 + K2;
  for (int i = threadIdx.x; i < K*NC; i += 256) Ws[i] = W[i];
  if (threadIdx.x < NC) bs[threadIdx.x] = bias[threadIdx.x];
  __syncthreads();
  int row = blockIdx.x*256 + threadIdx.x;
  if (row >= M) return;
  float acc[NC];
  #pragma unroll
  for (int n = 0; n < NC; ++n) acc[n] = bs[n];
  const float* a = A1 + (size_t)row*K1;
  for (int k = 0; k < K1; ++k){
    float av = a[k];
    if (relu_in) av = fmaxf(av, 0.f);
    #pragma unroll
    for (int n = 0; n < NC; ++n) acc[n] += av*Ws[k*NC + n];
  }
  if (A2){
    const float* a2 = A2 + (size_t)row*K2;
    for (int k = 0; k < K2; ++k){
      float av = a2[k];
      if (relu_in) av = fmaxf(av, 0.f);
      #pragma unroll
      for (int n = 0; n < NC; ++n) acc[n] += av*Ws[(K1 + k)*NC + n];
    }
  }
  #pragma unroll
  for (int n = 0; n < NC; ++n) out[(size_t)row*NC + n] = acc[n];
}

// ---------------- alpha reduction ----------------
__global__ __launch_bounds__(1024) void alpha_kernel(const float* __restrict__ base, const float* __restrict__ gate,
                                                     const float* __restrict__ y, const int* __restrict__ index,
                                                     float* __restrict__ alpha_out){
  __shared__ float r1[1024], r2[1024];
  int tid = threadIdx.x;
  float s1 = 0.f, sall = 0.f;
  for (int i = tid; i < NI*NC; i += 1024){
    int ii = i / NC, n = i - ii*NC;
    int r = index[ii];
    float yv = y[(size_t)r*NC + n];
    float b = base[(size_t)r*NC + n];
    float g = gate[(size_t)r*NC + n];
    float te = expf(-b*yv);
    sall += te;
    if (g*yv >= 0.f) s1 += te;
  }
  r1[tid] = s1; r2[tid] = sall;
  __syncthreads();
  for (int off = 512; off > 0; off >>= 1){
    if (tid < off){ r1[tid] += r1[tid+off]; r2[tid] += r2[tid+off]; }
    __syncthreads();
  }
  if (tid == 0){
    float s2 = r2[0] - r1[0];
    alpha_out[0] = 0.5f*logf(s2/r1[0]);
  }
}

__global__ void axpy_kernel(const float* __restrict__ a, const float* __restrict__ b,
                            const float* __restrict__ alpha, float* __restrict__ out, int n){
  int i = blockIdx.x*blockDim.x + threadIdx.x;
  if (i < n) out[i] = a[i] + alpha[0]*b[i];
}

// ---------------- host ----------------
extern "C" void kernel_launch(void* const* d_in, const int* in_sizes, int n_in,
                              void* d_out, int out_size, void* d_ws, size_t ws_size,
                              hipStream_t stream){
  const float* x     = (const float*)d_in[0];
  const float* y     = (const float*)d_in[1];
  const int*   index = (const int*)d_in[2];
  const int*   a1r = (const int*)d_in[3];  const int* a1c = (const int*)d_in[4];  const float* a1v = (const float*)d_in[5];
  const int*   a3r = (const int*)d_in[9];  const int* a3c = (const int*)d_in[10]; const float* a3v = (const float*)d_in[11];
  const int*   a4r = (const int*)d_in[12]; const int* a4c = (const int*)d_in[13]; const float* a4v = (const float*)d_in[14];
  const int*   a5r = (const int*)d_in[15]; const int* a5c = (const int*)d_in[16]; const float* a5v = (const float*)d_in[17];
  const float* w1  = (const float*)d_in[18]; const float* b1  = (const float*)d_in[19];
  const float* w2  = (const float*)d_in[20]; const float* b2  = (const float*)d_in[21];
  const float* w3  = (const float*)d_in[22]; const float* b3  = (const float*)d_in[23];
  const float* w4  = (const float*)d_in[24]; const float* b4  = (const float*)d_in[25];
  const float* w5  = (const float*)d_in[26]; const float* b5  = (const float*)d_in[27];
  const float* w6  = (const float*)d_in[28]; const float* b6  = (const float*)d_in[29];
  const float* w10 = (const float*)d_in[30]; const float* b10 = (const float*)d_in[31];
  const float* w11 = (const float*)d_in[32]; const float* b11 = (const float*)d_in[33];
  const float* w12 = (const float*)d_in[34]; const float* b12 = (const float*)d_in[35];
  const float* d1w = (const float*)d_in[36]; const float* d1b = (const float*)d_in[37];
  const float* d2w = (const float*)d_in[38]; const float* d2b = (const float*)d_in[39];
  const float* d3w = (const float*)d_in[40]; const float* d3b = (const float*)d_in[41];
  const float* d4w = (const float*)d_in[42]; const float* d4b = (const float*)d_in[43];
  const float* sw  = (const float*)d_in[44]; const float* sb  = (const float*)d_in[45];
  float* out = (float*)d_out;

  // ---- carve workspace (same layout/footprint class as proven round-0) ----
  char* p = (char*)d_ws;
  auto carve = [&](size_t bytes) -> char* {
    char* q = p;
    p += (bytes + 255) & ~size_t(255);
    return q;
  };
  float* S    = (float*)carve((size_t)NN*D1*4);   // layer-1 support (kept across x2/x3)
  float* SB   = (float*)carve((size_t)NN*D2*4);   // layer-2/3 support
  float* H1b  = (float*)carve((size_t)NN*D1*4);
  float* H2b  = (float*)carve((size_t)NN*D2*4);
  float* XB   = (float*)carve((size_t)NN*D3*4);   // x1 / x4 raw
  float* X2   = (float*)carve((size_t)NN*D3*4);
  float* X3   = (float*)carve((size_t)NN*D3*4);
  float* X1D  = (float*)carve((size_t)NN*NC*4);
  float* X4D  = (float*)carve((size_t)NN*NC*4);
  float* SIM  = (float*)carve((size_t)NN*NC*4);
  float* ALPHA= (float*)carve(256);
  int*   ROWP = (int*)carve((size_t)(NN+1)*4);
  int*   FILL = (int*)carve((size_t)NN*4);
  int*   CNT  = (int*)carve((size_t)NN*4);
  int*   CHUNK= (int*)carve((size_t)NN*4);
  int*   BSUM = (int*)carve(256*4);
  int*   CC   = (int*)carve((size_t)EE*4);
  float* CV   = (float*)carve((size_t)EE*4);
  (void)ws_size; (void)n_in; (void)in_sizes; (void)out_size;

  float* OUT_X2D = out;                 // 350000
  float* OUT_X3D = out + (size_t)NN*NC; // 350000
  float* OUT_P2  = out + (size_t)2*NN*NC;

  const int NB_SCAN = (NN + 255)/256;   // 196
  auto build_csr = [&](const int* r, const int* c, const float* v){
    hipMemsetAsync(CNT, 0, (size_t)NN*4, stream);
    hist_kernel<<<(EE+255)/256, 256, 0, stream>>>(r, CNT, EE);
    scan1_kernel<<<NB_SCAN, 256, 0, stream>>>(CNT, CHUNK, BSUM, NN);
    scan2_kernel<<<1, 256, 0, stream>>>(BSUM, NB_SCAN);
    scan3_kernel<<<NB_SCAN, 256, 0, stream>>>(CHUNK, BSUM, ROWP, FILL, NN, EE);
    scatter_kernel<<<(EE+255)/256, 256, 0, stream>>>(r, c, v, FILL, CC, CV, EE);
  };
  auto gemm = [&](const float* A, const float* B, float* C, int M, int N, int K){
    if (N == 128){
      gemm_fast_kernel<<<(M+127)/128, 256, 0, stream>>>(A, B, C, M, K);
    } else {
      dim3 g((N+63)/64, (M+63)/64);
      gemm_kernel<<<g, 256, 0, stream>>>(A, B, C, M, N, K);
    }
  };

  auto run_branch = [&](const int* ar, const int* ac, const float* av,
                        const float* Wa, const float* ba, const float* Wb, const float* bb,
                        const float* Wc, const float* bc,
                        const float* dW, const float* db,
                        float* xout, float* dout, bool compute_S){
    build_csr(ar, ac, av);
    if (compute_S) gemm(x, Wa, S, NN, D1, KF);
    spmm_kernel<128,1><<<(NN+3)/4, 256, 0, stream>>>(ROWP, CC, CV, S, ba, H1b);
    gemm(H1b, Wb, SB, NN, D2, D1);
    spmm_kernel<64,1><<<(NN+3)/4, 256, 0, stream>>>(ROWP, CC, CV, SB, bb, H2b);
    gemm(H2b, Wc, SB, NN, D3, D2);
    spmm_kernel<64,0><<<(NN+3)/4, 256, 0, stream>>>(ROWP, CC, CV, SB, bc, xout);
    dense7_kernel<<<(NN+255)/256, 256, 0, stream>>>(xout, nullptr, D3, 0, dW, db, dout, NN, 1);
  };

  // x1: adjacency a5, weights w1-w3, proj d1 -> X1D
  run_branch(a5r, a5c, a5v, w1, b1, w2, b2, w3, b3, d1w, d1b, XB, X1D, true);
  // x2: adjacency a4, weights w4-w6, proj d2 -> out[0]
  run_branch(a4r, a4c, a4v, w4, b4, w5, b5, w6, b6, d2w, d2b, X2, OUT_X2D, true);
  // x3: adjacency a3, SAME weights w4-w6 (S = x@w4 still valid!), proj d3 -> out[1]
  run_branch(a3r, a3c, a3v, w4, b4, w5, b5, w6, b6, d3w, d3b, X3, OUT_X3D, false);
  // x4: adjacency a1, weights w10-w12, proj d4 -> X4D
  run_branch(a1r, a1c, a1v, w10, b10, w11, b11, w12, b12, d4w, d4b, XB, X4D, true);

  // sim = [x2 | x3] @ sw + sb
  dense7_kernel<<<(NN+255)/256, 256, 0, stream>>>(X2, X3, D3, D3, sw, sb, SIM, NN, 0);

  // part1 = x4d + alpha(x4d, sim)*sim   (into OUT_P2)
  alpha_kernel<<<1, 1024, 0, stream>>>(X4D, SIM, y, index, ALPHA);
  axpy_kernel<<<((NN*NC)+255)/256, 256, 0, stream>>>(X4D, SIM, ALPHA, OUT_P2, NN*NC);
  // part2 = part1 + alpha(part1, x1d)*x1d  (in place)
  alpha_kernel<<<1, 1024, 0, stream>>>(OUT_P2, X1D, y, index, ALPHA+1);
  axpy_kernel<<<((NN*NC)+255)/256, 256, 0, stream>>>(OUT_P2, X1D, ALPHA+1, OUT_P2, NN*NC);
}

// Round 3
// 1695.876 us; speedup vs baseline: 1.4222x; 1.1816x over previous
//
#include <hip/hip_runtime.h>
#include <cstddef>

#define NN 50000      // nodes
#define EE 800000     // edges per adjacency
#define KF 500        // NFEAT
#define D1 128        // H2
#define D2 64         // H3
#define D3 64         // H4
#define NC 7          // classes
#define NI 5000       // index size

// ---------------- CSR build ----------------
__global__ void hist_kernel(const int* __restrict__ r, int* __restrict__ cnt, int n){
  int i = blockIdx.x*blockDim.x + threadIdx.x;
  if (i < n) atomicAdd(&cnt[r[i]], 1);
}

__global__ __launch_bounds__(256) void scan1_kernel(const int* __restrict__ cnt, int* __restrict__ chunk,
                                                    int* __restrict__ bsum, int n){
  __shared__ int buf[256];
  int tid = threadIdx.x;
  int i = blockIdx.x*256 + tid;
  int v = (i < n) ? cnt[i] : 0;
  buf[tid] = v;
  __syncthreads();
  for (int off = 1; off < 256; off <<= 1){
    int t = (tid >= off) ? buf[tid - off] : 0;
    __syncthreads();
    buf[tid] += t;
    __syncthreads();
  }
  if (i < n) chunk[i] = buf[tid] - v;
  if (tid == 255) bsum[blockIdx.x] = buf[255];
}
__global__ __launch_bounds__(256) void scan2_kernel(int* __restrict__ bsum, int nb){
  __shared__ int buf[256];
  int tid = threadIdx.x;
  int v = (tid < nb) ? bsum[tid] : 0;
  buf[tid] = v;
  __syncthreads();
  for (int off = 1; off < 256; off <<= 1){
    int t = (tid >= off) ? buf[tid - off] : 0;
    __syncthreads();
    buf[tid] += t;
    __syncthreads();
  }
  if (tid < nb) bsum[tid] = buf[tid] - v;
}
__global__ void scan3_kernel(const int* __restrict__ chunk, const int* __restrict__ bsum,
                             int* __restrict__ row_ptr, int* __restrict__ fill, int n, int total){
  int i = blockIdx.x*256 + threadIdx.x;
  if (i < n){
    int e = chunk[i] + bsum[blockIdx.x];
    row_ptr[i] = e; fill[i] = e;
  }
  if (i == 0) row_ptr[n] = total;
}

__global__ void scatter_kernel(const int* __restrict__ r, const int* __restrict__ c, const float* __restrict__ v,
                               int* __restrict__ fill, int2* __restrict__ ecv, int n){
  int i = blockIdx.x*blockDim.x + threadIdx.x;
  if (i < n){
    int p = atomicAdd(&fill[r[i]], 1);
    ecv[p] = make_int2(c[i], __float_as_int(v[i]));
  }
}

// ---------------- fused 3x fp32 GEMM, N=128 each: Cj[M,128] = A[M,K] @ Bj[K,128] ----------------
__global__ __launch_bounds__(256) void gemm3_kernel(const float* __restrict__ A,
                                                    const float* __restrict__ B0, const float* __restrict__ B1,
                                                    const float* __restrict__ B2,
                                                    float* __restrict__ C0, float* __restrict__ C1,
                                                    float* __restrict__ C2, int M, int K, int nb){
  int which = blockIdx.x / nb;
  int rb    = blockIdx.x % nb;
  const float* B = (which == 0) ? B0 : (which == 1) ? B1 : B2;
  float*       C = (which == 0) ? C0 : (which == 1) ? C1 : C2;

  __shared__ __align__(16) float As[16][132];
  __shared__ __align__(16) float Bs[16][132];
  int tid = threadIdx.x;
  int tx = tid & 15, ty = tid >> 4;
  int row0 = rb*128;
  float acc[8][8] = {};
  int ar = tid >> 2, akq = tid & 3;
  for (int k0 = 0; k0 < K; k0 += 16){
    #pragma unroll
    for (int h = 0; h < 2; ++h){
      int r = ar + h*64;
      int gr = row0 + r;
      int gk = k0 + akq*4;
      float4 av = make_float4(0.f,0.f,0.f,0.f);
      if (gr < M){
        if (gk + 4 <= K) av = *reinterpret_cast<const float4*>(&A[(size_t)gr*K + gk]);
        else {
          float t0 = (gk   < K) ? A[(size_t)gr*K + gk  ] : 0.f;
          float t1 = (gk+1 < K) ? A[(size_t)gr*K + gk+1] : 0.f;
          float t2 = (gk+2 < K) ? A[(size_t)gr*K + gk+2] : 0.f;
          float t3 = (gk+3 < K) ? A[(size_t)gr*K + gk+3] : 0.f;
          av = make_float4(t0,t1,t2,t3);
        }
      }
      As[akq*4+0][r] = av.x; As[akq*4+1][r] = av.y;
      As[akq*4+2][r] = av.z; As[akq*4+3][r] = av.w;
    }
    {
      int n = (tid & 31)*4;
      #pragma unroll
      for (int kb = tid >> 5; kb < 16; kb += 8){
        int gk = k0 + kb;
        float4 bv = make_float4(0.f,0.f,0.f,0.f);
        if (gk < K) bv = *reinterpret_cast<const float4*>(&B[(size_t)gk*128 + n]);
        *reinterpret_cast<float4*>(&Bs[kb][n]) = bv;
      }
    }
    __syncthreads();
    #pragma unroll
    for (int kk = 0; kk < 16; ++kk){
      float a[8], b[8];
      *(float4*)&a[0] = *(const float4*)&As[kk][ty*4];
      *(float4*)&a[4] = *(const float4*)&As[kk][64 + ty*4];
      *(float4*)&b[0] = *(const float4*)&Bs[kk][tx*4];
      *(float4*)&b[4] = *(const float4*)&Bs[kk][64 + tx*4];
      #pragma unroll
      for (int m = 0; m < 8; ++m)
        #pragma unroll
        for (int n2 = 0; n2 < 8; ++n2)
          acc[m][n2] += a[m]*b[n2];
    }
    __syncthreads();
  }
  #pragma unroll
  for (int m = 0; m < 8; ++m){
    int r = (m < 4) ? (ty*4 + m) : (64 + ty*4 + (m-4));
    int gr = row0 + r;
    if (gr >= M) continue;
    *reinterpret_cast<float4*>(&C[(size_t)gr*128 + tx*4])      = *(float4*)&acc[m][0];
    *reinterpret_cast<float4*>(&C[(size_t)gr*128 + 64 + tx*4]) = *(float4*)&acc[m][4];
  }
}

// single-GEMM wrapper (fallback path), N=128
__global__ __launch_bounds__(256) void gemm_fast_kernel(const float* __restrict__ A, const float* __restrict__ B,
                                                        float* __restrict__ C, int M, int K){
  // delegate body by treating as which==0
  __shared__ __align__(16) float As[16][132];
  __shared__ __align__(16) float Bs[16][132];
  int tid = threadIdx.x;
  int tx = tid & 15, ty = tid >> 4;
  int row0 = blockIdx.x*128;
  float acc[8][8] = {};
  int ar = tid >> 2, akq = tid & 3;
  for (int k0 = 0; k0 < K; k0 += 16){
    #pragma unroll
    for (int h = 0; h < 2; ++h){
      int r = ar + h*64;
      int gr = row0 + r;
      int gk = k0 + akq*4;
      float4 av = make_float4(0.f,0.f,0.f,0.f);
      if (gr < M){
        if (gk + 4 <= K) av = *reinterpret_cast<const float4*>(&A[(size_t)gr*K + gk]);
        else {
          float t0 = (gk   < K) ? A[(size_t)gr*K + gk  ] : 0.f;
          float t1 = (gk+1 < K) ? A[(size_t)gr*K + gk+1] : 0.f;
          float t2 = (gk+2 < K) ? A[(size_t)gr*K + gk+2] : 0.f;
          float t3 = (gk+3 < K) ? A[(size_t)gr*K + gk+3] : 0.f;
          av = make_float4(t0,t1,t2,t3);
        }
      }
      As[akq*4+0][r] = av.x; As[akq*4+1][r] = av.y;
      As[akq*4+2][r] = av.z; As[akq*4+3][r] = av.w;
    }
    {
      int n = (tid & 31)*4;
      #pragma unroll
      for (int kb = tid >> 5; kb < 16; kb += 8){
        int gk = k0 + kb;
        float4 bv = make_float4(0.f,0.f,0.f,0.f);
        if (gk < K) bv = *reinterpret_cast<const float4*>(&B[(size_t)gk*128 + n]);
        *reinterpret_cast<float4*>(&Bs[kb][n]) = bv;
      }
    }
    __syncthreads();
    #pragma unroll
    for (int kk = 0; kk < 16; ++kk){
      float a[8], b[8];
      *(float4*)&a[0] = *(const float4*)&As[kk][ty*4];
      *(float4*)&a[4] = *(const float4*)&As[kk][64 + ty*4];
      *(float4*)&b[0] = *(const float4*)&Bs[kk][tx*4];
      *(float4*)&b[4] = *(const float4*)&Bs[kk][64 + tx*4];
      #pragma unroll
      for (int m = 0; m < 8; ++m)
        #pragma unroll
        for (int n2 = 0; n2 < 8; ++n2)
          acc[m][n2] += a[m]*b[n2];
    }
    __syncthreads();
  }
  #pragma unroll
  for (int m = 0; m < 8; ++m){
    int r = (m < 4) ? (ty*4 + m) : (64 + ty*4 + (m-4));
    int gr = row0 + r;
    if (gr >= M) continue;
    *reinterpret_cast<float4*>(&C[(size_t)gr*128 + tx*4])      = *(float4*)&acc[m][0];
    *reinterpret_cast<float4*>(&C[(size_t)gr*128 + 64 + tx*4]) = *(float4*)&acc[m][4];
  }
}

// ---------------- generic fp32 tiled GEMM (64x64 tile) for N<=64 ----------------
__global__ __launch_bounds__(256) void gemm_kernel(const float* __restrict__ A, const float* __restrict__ B,
                                                   float* __restrict__ C, int M, int N, int K){
  __shared__ __align__(16) float As[16][68];
  __shared__ __align__(16) float Bs[16][68];
  int tid = threadIdx.x;
  int tx = tid & 15, ty = tid >> 4;
  int row0 = blockIdx.y*64, col0 = blockIdx.x*64;
  float acc[4][4] = {};
  for (int k0 = 0; k0 < K; k0 += 16){
    for (int l = tid; l < 64*16; l += 256){
      int i = l >> 4, j = l & 15;
      int gr = row0 + i, gk = k0 + j;
      As[j][i] = (gr < M && gk < K) ? A[(size_t)gr*K + gk] : 0.f;
    }
    for (int l = tid; l < 16*64; l += 256){
      int kk = l >> 6, n = l & 63;
      int gk = k0 + kk, gc = col0 + n;
      Bs[kk][n] = (gk < K && gc < N) ? B[(size_t)gk*N + gc] : 0.f;
    }
    __syncthreads();
    #pragma unroll
    for (int kk = 0; kk < 16; ++kk){
      float4 av = *reinterpret_cast<const float4*>(&As[kk][ty*4]);
      float4 bv = *reinterpret_cast<const float4*>(&Bs[kk][tx*4]);
      float a4[4] = {av.x, av.y, av.z, av.w};
      float b4[4] = {bv.x, bv.y, bv.z, bv.w};
      #pragma unroll
      for (int m = 0; m < 4; ++m)
        #pragma unroll
        for (int n = 0; n < 4; ++n)
          acc[m][n] += a4[m]*b4[n];
    }
    __syncthreads();
  }
  #pragma unroll
  for (int m = 0; m < 4; ++m){
    int gr = row0 + ty*4 + m;
    if (gr < M){
      #pragma unroll
      for (int n = 0; n < 4; ++n){
        int gc = col0 + tx*4 + n;
        if (gc < N) C[(size_t)gr*N + gc] = acc[m][n];
      }
    }
  }
}

// ---------------- gather SpMM with lane-broadcast edge metadata ----------------
template<int H, int RELU>
__global__ __launch_bounds__(256) void spmm_kernel(const int* __restrict__ row_ptr, const int2* __restrict__ ecv,
                                                   const float* __restrict__ S,
                                                   const float* __restrict__ bias, float* __restrict__ out){
  int row = blockIdx.x*4 + (threadIdx.x >> 6);
  int lane = threadIdx.x & 63;
  if (row >= NN) return;
  int p0 = row_ptr[row], p1 = row_ptr[row+1];
  float2 acc2 = make_float2(0.f, 0.f);
  float acc1 = 0.f;
  for (int base = p0; base < p1; base += 64){
    int nrem = p1 - base; if (nrem > 64) nrem = 64;
    int2 ev = (lane < nrem) ? ecv[base + lane] : make_int2(0, 0);
    for (int i = 0; i < nrem; ++i){
      int c   = __shfl(ev.x, i);
      float v = __int_as_float(__shfl(ev.y, i));
      if (H == 128){
        float2 s = ((const float2*)(S + (size_t)c*128))[lane];
        acc2.x += v*s.x; acc2.y += v*s.y;
      } else {
        acc1 += v * S[(size_t)c*64 + lane];
      }
    }
  }
  if (H == 128){
    float2 b = ((const float2*)bias)[lane];
    acc2.x += b.x; acc2.y += b.y;
    if (RELU){ acc2.x = fmaxf(acc2.x, 0.f); acc2.y = fmaxf(acc2.y, 0.f); }
    ((float2*)(out + (size_t)row*128))[lane] = acc2;
  } else {
    acc1 += bias[lane];
    if (RELU) acc1 = fmaxf(acc1, 0.f);
    out[(size_t)row*64 + lane] = acc1;
  }
}

// ---------------- tall-skinny dense: out[M,7] = (relu?)([A1|A2]) @ W + b ----------------
__global__ __launch_bounds__(256) void dense7_kernel(const float* __restrict__ A1, const float* __restrict__ A2,
                                                     int K1, int K2, const float* __restrict__ W,
                                                     const float* __restrict__ bias, float* __restrict__ out,
                                                     int M, int relu_in){
  __shared__ float Ws[128*NC];
  __shared__ float bs[NC];
  int K = K1 + K2;
  for (int i = threadIdx.x; i < K*NC; i += 256) Ws[i] = W[i];
  if (threadIdx.x < NC) bs[threadIdx.x] = bias[threadIdx.x];
  __syncthreads();
  int row = blockIdx.x*256 + threadIdx.x;
  if (row >= M) return;
  float acc[NC];
  #pragma unroll
  for (int n = 0; n < NC; ++n) acc[n] = bs[n];
  const float* a = A1 + (size_t)row*K1;
  for (int k = 0; k < K1; ++k){
    float av = a[k];
    if (relu_in) av = fmaxf(av, 0.f);
    #pragma unroll
    for (int n = 0; n < NC; ++n) acc[n] += av*Ws[k*NC + n];
  }
  if (A2){
    const float* a2 = A2 + (size_t)row*K2;
    for (int k = 0; k < K2; ++k){
      float av = a2[k];
      if (relu_in) av = fmaxf(av, 0.f);
      #pragma unroll
      for (int n = 0; n < NC; ++n) acc[n] += av*Ws[(K1 + k)*NC + n];
    }
  }
  #pragma unroll
  for (int n = 0; n < NC; ++n) out[(size_t)row*NC + n] = acc[n];
}

// ---------------- alpha reduction ----------------
__global__ __launch_bounds__(1024) void alpha_kernel(const float* __restrict__ base, const float* __restrict__ gate,
                                                     const float* __restrict__ y, const int* __restrict__ index,
                                                     float* __restrict__ alpha_out){
  __shared__ float r1[1024], r2[1024];
  int tid = threadIdx.x;
  float s1 = 0.f, sall = 0.f;
  for (int i = tid; i < NI*NC; i += 1024){
    int ii = i / NC, n = i - ii*NC;
    int r = index[ii];
    float yv = y[(size_t)r*NC + n];
    float b = base[(size_t)r*NC + n];
    float g = gate[(size_t)r*NC + n];
    float te = expf(-b*yv);
    sall += te;
    if (g*yv >= 0.f) s1 += te;
  }
  r1[tid] = s1; r2[tid] = sall;
  __syncthreads();
  for (int off = 512; off > 0; off >>= 1){
    if (tid < off){ r1[tid] += r1[tid+off]; r2[tid] += r2[tid+off]; }
    __syncthreads();
  }
  if (tid == 0){
    float s2 = r2[0] - r1[0];
    alpha_out[0] = 0.5f*logf(s2/r1[0]);
  }
}

__global__ void axpy_kernel(const float* __restrict__ a, const float* __restrict__ b,
                            const float* __restrict__ alpha, float* __restrict__ out, int n){
  int i = blockIdx.x*blockDim.x + threadIdx.x;
  if (i < n) out[i] = a[i] + alpha[0]*b[i];
}

// ---------------- host ----------------
extern "C" void kernel_launch(void* const* d_in, const int* in_sizes, int n_in,
                              void* d_out, int out_size, void* d_ws, size_t ws_size,
                              hipStream_t stream){
  const float* x     = (const float*)d_in[0];
  const float* y     = (const float*)d_in[1];
  const int*   index = (const int*)d_in[2];
  const int*   a1r = (const int*)d_in[3];  const int* a1c = (const int*)d_in[4];  const float* a1v = (const float*)d_in[5];
  const int*   a3r = (const int*)d_in[9];  const int* a3c = (const int*)d_in[10]; const float* a3v = (const float*)d_in[11];
  const int*   a4r = (const int*)d_in[12]; const int* a4c = (const int*)d_in[13]; const float* a4v = (const float*)d_in[14];
  const int*   a5r = (const int*)d_in[15]; const int* a5c = (const int*)d_in[16]; const float* a5v = (const float*)d_in[17];
  const float* w1  = (const float*)d_in[18]; const float* b1  = (const float*)d_in[19];
  const float* w2  = (const float*)d_in[20]; const float* b2  = (const float*)d_in[21];
  const float* w3  = (const float*)d_in[22]; const float* b3  = (const float*)d_in[23];
  const float* w4  = (const float*)d_in[24]; const float* b4  = (const float*)d_in[25];
  const float* w5  = (const float*)d_in[26]; const float* b5  = (const float*)d_in[27];
  const float* w6  = (const float*)d_in[28]; const float* b6  = (const float*)d_in[29];
  const float* w10 = (const float*)d_in[30]; const float* b10 = (const float*)d_in[31];
  const float* w11 = (const float*)d_in[32]; const float* b11 = (const float*)d_in[33];
  const float* w12 = (const float*)d_in[34]; const float* b12 = (const float*)d_in[35];
  const float* d1w = (const float*)d_in[36]; const float* d1b = (const float*)d_in[37];
  const float* d2w = (const float*)d_in[38]; const float* d2b = (const float*)d_in[39];
  const float* d3w = (const float*)d_in[40]; const float* d3b = (const float*)d_in[41];
  const float* d4w = (const float*)d_in[42]; const float* d4b = (const float*)d_in[43];
  const float* sw  = (const float*)d_in[44]; const float* sb  = (const float*)d_in[45];
  float* out = (float*)d_out;

  // ---- carve workspace; optional buffers LAST so we can fall back ----
  char* p = (char*)d_ws;
  auto carve = [&](size_t bytes) -> char* {
    char* q = p;
    p += (bytes + 255) & ~size_t(255);
    return q;
  };
  float* S1   = (float*)carve((size_t)NN*D1*4);
  float* SB   = (float*)carve((size_t)NN*D2*4);
  float* H1b  = (float*)carve((size_t)NN*D1*4);
  float* H2b  = (float*)carve((size_t)NN*D2*4);
  float* XB   = (float*)carve((size_t)NN*D3*4);
  float* X2   = (float*)carve((size_t)NN*D3*4);
  float* X3   = (float*)carve((size_t)NN*D3*4);
  float* X1D  = (float*)carve((size_t)NN*NC*4);
  float* X4D  = (float*)carve((size_t)NN*NC*4);
  float* SIM  = (float*)carve((size_t)NN*NC*4);
  float* ALPHA= (float*)carve(256);
  int*   ROWP = (int*)carve((size_t)(NN+1)*4);
  int*   FILL = (int*)carve((size_t)NN*4);
  int*   CNT  = (int*)carve((size_t)NN*4);
  int*   CHUNK= (int*)carve((size_t)NN*4);
  int*   BSUM = (int*)carve(256*4);
  int2*  ECV  = (int2*)carve((size_t)EE*8);
  // optional (fused layer-1 GEMM) buffers:
  float* S4   = (float*)carve((size_t)NN*D1*4);
  float* S10  = (float*)carve((size_t)NN*D1*4);
  bool fused = ((size_t)(p - (char*)d_ws) <= ws_size);
  if (!fused){ S4 = S1; S10 = S1; }
  (void)n_in; (void)in_sizes; (void)out_size;

  float* OUT_X2D = out;
  float* OUT_X3D = out + (size_t)NN*NC;
  float* OUT_P2  = out + (size_t)2*NN*NC;

  const int NB_SCAN = (NN + 255)/256;
  auto build_csr = [&](const int* r, const int* c, const float* v){
    hipMemsetAsync(CNT, 0, (size_t)NN*4, stream);
    hist_kernel<<<(EE+255)/256, 256, 0, stream>>>(r, CNT, EE);
    scan1_kernel<<<NB_SCAN, 256, 0, stream>>>(CNT, CHUNK, BSUM, NN);
    scan2_kernel<<<1, 256, 0, stream>>>(BSUM, NB_SCAN);
    scan3_kernel<<<NB_SCAN, 256, 0, stream>>>(CHUNK, BSUM, ROWP, FILL, NN, EE);
    scatter_kernel<<<(EE+255)/256, 256, 0, stream>>>(r, c, v, FILL, ECV, EE);
  };
  auto gemm = [&](const float* A, const float* B, float* C, int M, int N, int K){
    dim3 g((N+63)/64, (M+63)/64);
    gemm_kernel<<<g, 256, 0, stream>>>(A, B, C, M, N, K);
  };

  const int NB128 = (NN + 127)/128;  // 391
  if (fused){
    gemm3_kernel<<<3*NB128, 256, 0, stream>>>(x, w1, w4, w10, S1, S4, S10, NN, KF, NB128);
  }

  auto run_branch = [&](const int* ar, const int* ac, const float* av, const float* S_in, const float* Wa,
                        const float* ba, const float* Wb, const float* bb,
                        const float* Wc, const float* bc,
                        const float* dW, const float* db,
                        float* xout, float* dout, bool need_gemm1){
    build_csr(ar, ac, av);
    if (!fused && need_gemm1){
      gemm_fast_kernel<<<NB128, 256, 0, stream>>>(x, Wa, (float*)S_in, NN, KF);
    }
    spmm_kernel<128,1><<<(NN+3)/4, 256, 0, stream>>>(ROWP, ECV, S_in, ba, H1b);
    gemm(H1b, Wb, SB, NN, D2, D1);
    spmm_kernel<64,1><<<(NN+3)/4, 256, 0, stream>>>(ROWP, ECV, SB, bb, H2b);
    gemm(H2b, Wc, SB, NN, D3, D2);
    spmm_kernel<64,0><<<(NN+3)/4, 256, 0, stream>>>(ROWP, ECV, SB, bc, xout);
    dense7_kernel<<<(NN+255)/256, 256, 0, stream>>>(xout, nullptr, D3, 0, dW, db, dout, NN, 1);
  };

  // x1: adjacency a5, weights w1-w3 (S1 = x@w1)
  run_branch(a5r, a5c, a5v, S1, w1, b1, w2, b2, w3, b3, d1w, d1b, XB, X1D, true);
  // x2: adjacency a4, weights w4-w6 (S4 = x@w4)
  run_branch(a4r, a4c, a4v, S4, w4, b4, w5, b5, w6, b6, d2w, d2b, X2, OUT_X2D, true);
  // x3: adjacency a3, same weights w4-w6 -> S4 still valid (in fallback S4==S1 holds x@w4)
  run_branch(a3r, a3c, a3v, S4, w4, b4, w5, b5, w6, b6, d3w, d3b, X3, OUT_X3D, false);
  // x4: adjacency a1, weights w10-w12 (S10 = x@w10)
  run_branch(a1r, a1c, a1v, S10, w10, b10, w11, b11, w12, b12, d4w, d4b, XB, X4D, true);

  // sim = [x2 | x3] @ sw + sb
  dense7_kernel<<<(NN+255)/256, 256, 0, stream>>>(X2, X3, D3, D3, sw, sb, SIM, NN, 0);

  // part1 = x4d + alpha(x4d, sim)*sim
  alpha_kernel<<<1, 1024, 0, stream>>>(X4D, SIM, y, index, ALPHA);
  axpy_kernel<<<((NN*NC)+255)/256, 256, 0, stream>>>(X4D, SIM, ALPHA, OUT_P2, NN*NC);
  // part2 = part1 + alpha(part1, x1d)*x1d
  alpha_kernel<<<1, 1024, 0, stream>>>(OUT_P2, X1D, y, index, ALPHA+1);
  axpy_kernel<<<((NN*NC)+255)/256, 256, 0, stream>>>(OUT_P2, X1D, ALPHA+1, OUT_P2, NN*NC);
}

// Round 5
// 1416.761 us; speedup vs baseline: 1.7024x; 1.1970x over previous
//
#include <hip/hip_runtime.h>
#include <cstddef>

#define NN 50000      // nodes
#define EE 800000     // edges per adjacency
#define KF 500        // NFEAT
#define D1 128        // H2
#define D2 64         // H3
#define D3 64         // H4
#define NC 7          // classes
#define NIDX 5000     // index size

typedef __attribute__((ext_vector_type(8))) short bf16x8;
typedef __attribute__((ext_vector_type(4))) float f32x4;
typedef __attribute__((ext_vector_type(4))) unsigned short u16x4;
typedef __attribute__((ext_vector_type(8))) unsigned short u16x8;

__device__ __forceinline__ unsigned short bfh(float f){
  unsigned u = __float_as_uint(f);
  u += 0x7FFFu + ((u >> 16) & 1u);
  return (unsigned short)(u >> 16);
}
__device__ __forceinline__ void bfsplit(float a, unsigned short& h, unsigned short& l){
  h = bfh(a);
  float r = a - __uint_as_float(((unsigned)h) << 16);
  l = bfh(r);
}

// ---------------- CSR build ----------------
__global__ void hist_kernel(const int* __restrict__ r, int* __restrict__ cnt, int n){
  int i = blockIdx.x*blockDim.x + threadIdx.x;
  if (i < n) atomicAdd(&cnt[r[i]], 1);
}

__global__ __launch_bounds__(256) void scan1_kernel(const int* __restrict__ cnt, int* __restrict__ chunk,
                                                    int* __restrict__ bsum, int n){
  __shared__ int buf[256];
  int tid = threadIdx.x;
  int i = blockIdx.x*256 + tid;
  int v = (i < n) ? cnt[i] : 0;
  buf[tid] = v;
  __syncthreads();
  for (int off = 1; off < 256; off <<= 1){
    int t = (tid >= off) ? buf[tid - off] : 0;
    __syncthreads();
    buf[tid] += t;
    __syncthreads();
  }
  if (i < n) chunk[i] = buf[tid] - v;
  if (tid == 255) bsum[blockIdx.x] = buf[255];
}
__global__ __launch_bounds__(256) void scan2_kernel(int* __restrict__ bsum, int nb){
  __shared__ int buf[256];
  int tid = threadIdx.x;
  int v = (tid < nb) ? bsum[tid] : 0;
  buf[tid] = v;
  __syncthreads();
  for (int off = 1; off < 256; off <<= 1){
    int t = (tid >= off) ? buf[tid - off] : 0;
    __syncthreads();
    buf[tid] += t;
    __syncthreads();
  }
  if (tid < nb) bsum[tid] = buf[tid] - v;
}
__global__ void scan3_kernel(const int* __restrict__ chunk, const int* __restrict__ bsum,
                             int* __restrict__ row_ptr, int* __restrict__ fill, int n, int total){
  int i = blockIdx.x*256 + threadIdx.x;
  if (i < n){
    int e = chunk[i] + bsum[blockIdx.x];
    row_ptr[i] = e; fill[i] = e;
  }
  if (i == 0) row_ptr[n] = total;
}

__global__ void scatter_kernel(const int* __restrict__ r, const int* __restrict__ c, const float* __restrict__ v,
                               int* __restrict__ fill, int2* __restrict__ ecv, int n){
  int i = blockIdx.x*blockDim.x + threadIdx.x;
  if (i < n){
    int p = atomicAdd(&fill[r[i]], 1);
    ecv[p] = make_int2(c[i], __float_as_int(v[i]));
  }
}

// ---------------- weight transpose + bf16 split: W[K][N] -> Wt_hi/lo[N][Kp] ----------------
__global__ __launch_bounds__(256) void wtc3_kernel(
    const float* __restrict__ W0, const float* __restrict__ W1, const float* __restrict__ W2,
    unsigned short* __restrict__ H0, unsigned short* __restrict__ L0,
    unsigned short* __restrict__ H1, unsigned short* __restrict__ L1,
    unsigned short* __restrict__ H2, unsigned short* __restrict__ L2,
    int K, int N, int Kp){
  int w = blockIdx.y;
  const float* W = (w==0)?W0:(w==1)?W1:W2;
  unsigned short* H = (w==0)?H0:(w==1)?H1:H2;
  unsigned short* L = (w==0)?L0:(w==1)?L1:L2;
  int n = blockIdx.x;
  for (int k = threadIdx.x; k < Kp; k += 256){
    float v = (k < K) ? W[(size_t)k*N + n] : 0.f;
    unsigned short h, l; bfsplit(v, h, l);
    H[(size_t)n*Kp + k] = h;
    L[(size_t)n*Kp + k] = l;
  }
}

// ---------------- split-bf16 MFMA GEMM: C[M,BN] = A[M,K] @ B, B pre-split [BN][Kp] ----------------
// 128-row M tile, BK=32, 4 waves (2x2). ngemm sub-GEMMs interleaved (which = bid % ngemm)
// so blocks sharing an A-panel are dispatch-adjacent (A fetched ~once via L2/L3).
template<int BN>
__global__ __launch_bounds__(256) void mfma_gemm_kernel(
    const float* __restrict__ A,
    const unsigned short* __restrict__ Bh0, const unsigned short* __restrict__ Bl0,
    const unsigned short* __restrict__ Bh1, const unsigned short* __restrict__ Bl1,
    const unsigned short* __restrict__ Bh2, const unsigned short* __restrict__ Bl2,
    float* __restrict__ C0, float* __restrict__ C1, float* __restrict__ C2,
    int M, int K, int Kp, int ngemm){
  constexpr int LD = 40;        // 32 k + 8 pad (elements) -> <=2-way LDS bank conflicts
  constexpr int NFR = BN/32;    // n-fragments per wave
  __shared__ __align__(16) unsigned short Ah[128*LD], Al[128*LD];
  __shared__ __align__(16) unsigned short Bhs[BN*LD], Bls[BN*LD];

  int which = blockIdx.x % ngemm;
  int rb    = blockIdx.x / ngemm;
  const unsigned short* Bh = (which==0)?Bh0:(which==1)?Bh1:Bh2;
  const unsigned short* Bl = (which==0)?Bl0:(which==1)?Bl1:Bl2;
  float* C = (which==0)?C0:(which==1)?C1:C2;

  int tid = threadIdx.x;
  int lane = tid & 63, wid = tid >> 6;
  int wr = wid >> 1, wc = wid & 1;
  int row0 = rb*128;

  f32x4 acc[4][NFR];
  #pragma unroll
  for (int i = 0; i < 4; ++i)
    #pragma unroll
    for (int j = 0; j < NFR; ++j) acc[i][j] = (f32x4){0.f,0.f,0.f,0.f};

  int sa_m = tid >> 3, sa_j = tid & 7;   // A staging: 32 rows x 8 k-quads per pass
  int sb_n = tid >> 2, sb_j = tid & 3;   // B staging: 64 rows x 4 oct-groups per pass
  int fr_off = (lane & 15)*LD + (lane >> 4)*8;  // fragment base (element units)

  for (int k0 = 0; k0 < K; k0 += 32){
    // ---- stage A (fp32 -> hi/lo bf16), K assumed %4==0 ----
    #pragma unroll
    for (int p = 0; p < 4; ++p){
      int m = sa_m + p*32;
      int gr = row0 + m, gk = k0 + sa_j*4;
      float4 v = make_float4(0.f,0.f,0.f,0.f);
      if (gr < M && gk < K) v = *reinterpret_cast<const float4*>(&A[(size_t)gr*K + gk]);
      unsigned short h0,h1,h2,h3,l0,l1,l2,l3;
      bfsplit(v.x,h0,l0); bfsplit(v.y,h1,l1); bfsplit(v.z,h2,l2); bfsplit(v.w,h3,l3);
      u16x4 hv = {h0,h1,h2,h3}, lv = {l0,l1,l2,l3};
      *reinterpret_cast<u16x4*>(&Ah[m*LD + sa_j*4]) = hv;
      *reinterpret_cast<u16x4*>(&Al[m*LD + sa_j*4]) = lv;
    }
    // ---- stage B (already bf16 planes, padded to Kp) ----
    #pragma unroll
    for (int p = 0; p < BN/64; ++p){
      int n = sb_n + p*64;
      int gk = k0 + sb_j*8;
      u16x8 hv = *reinterpret_cast<const u16x8*>(&Bh[(size_t)n*Kp + gk]);
      u16x8 lv = *reinterpret_cast<const u16x8*>(&Bl[(size_t)n*Kp + gk]);
      *reinterpret_cast<u16x8*>(&Bhs[n*LD + sb_j*8]) = hv;
      *reinterpret_cast<u16x8*>(&Bls[n*LD + sb_j*8]) = lv;
    }
    __syncthreads();
    bf16x8 ah[4], al[4], bh[NFR], bl[NFR];
    #pragma unroll
    for (int mi = 0; mi < 4; ++mi){
      int off = (wr*64 + mi*16)*LD + fr_off;
      ah[mi] = *reinterpret_cast<const bf16x8*>(&Ah[off]);
      al[mi] = *reinterpret_cast<const bf16x8*>(&Al[off]);
    }
    #pragma unroll
    for (int ni = 0; ni < NFR; ++ni){
      int off = (wc*(BN/2) + ni*16)*LD + fr_off;
      bh[ni] = *reinterpret_cast<const bf16x8*>(&Bhs[off]);
      bl[ni] = *reinterpret_cast<const bf16x8*>(&Bls[off]);
    }
    #pragma unroll
    for (int mi = 0; mi < 4; ++mi)
      #pragma unroll
      for (int ni = 0; ni < NFR; ++ni){
        acc[mi][ni] = __builtin_amdgcn_mfma_f32_16x16x32_bf16(ah[mi], bh[ni], acc[mi][ni], 0, 0, 0);
        acc[mi][ni] = __builtin_amdgcn_mfma_f32_16x16x32_bf16(ah[mi], bl[ni], acc[mi][ni], 0, 0, 0);
        acc[mi][ni] = __builtin_amdgcn_mfma_f32_16x16x32_bf16(al[mi], bh[ni], acc[mi][ni], 0, 0, 0);
      }
    __syncthreads();
  }
  // ---- epilogue: C/D layout col=lane&15, row=(lane>>4)*4+i ----
  #pragma unroll
  for (int mi = 0; mi < 4; ++mi){
    int rowb = row0 + wr*64 + mi*16 + (lane >> 4)*4;
    #pragma unroll
    for (int ni = 0; ni < NFR; ++ni){
      int col = wc*(BN/2) + ni*16 + (lane & 15);
      #pragma unroll
      for (int i = 0; i < 4; ++i){
        int r = rowb + i;
        if (r < M) C[(size_t)r*BN + col] = acc[mi][ni][i];
      }
    }
  }
}

// ---------------- gather SpMM with lane-broadcast edge metadata ----------------
template<int H, int RELU>
__global__ __launch_bounds__(256) void spmm_kernel(const int* __restrict__ row_ptr, const int2* __restrict__ ecv,
                                                   const float* __restrict__ S,
                                                   const float* __restrict__ bias, float* __restrict__ out){
  int row = blockIdx.x*4 + (threadIdx.x >> 6);
  int lane = threadIdx.x & 63;
  if (row >= NN) return;
  int p0 = row_ptr[row], p1 = row_ptr[row+1];
  float2 acc2 = make_float2(0.f, 0.f);
  float acc1 = 0.f;
  for (int base = p0; base < p1; base += 64){
    int nrem = p1 - base; if (nrem > 64) nrem = 64;
    int2 ev = (lane < nrem) ? ecv[base + lane] : make_int2(0, 0);
    for (int i = 0; i < nrem; ++i){
      int c   = __shfl(ev.x, i);
      float v = __int_as_float(__shfl(ev.y, i));
      if (H == 128){
        float2 s = ((const float2*)(S + (size_t)c*128))[lane];
        acc2.x += v*s.x; acc2.y += v*s.y;
      } else {
        acc1 += v * S[(size_t)c*64 + lane];
      }
    }
  }
  if (H == 128){
    float2 b = ((const float2*)bias)[lane];
    acc2.x += b.x; acc2.y += b.y;
    if (RELU){ acc2.x = fmaxf(acc2.x, 0.f); acc2.y = fmaxf(acc2.y, 0.f); }
    ((float2*)(out + (size_t)row*128))[lane] = acc2;
  } else {
    acc1 += bias[lane];
    if (RELU) acc1 = fmaxf(acc1, 0.f);
    out[(size_t)row*64 + lane] = acc1;
  }
}

// ---------------- tall-skinny dense: out[M,7] = (relu?)([A1|A2]) @ W + b ----------------
__global__ __launch_bounds__(256) void dense7_kernel(const float* __restrict__ A1, const float* __restrict__ A2,
                                                     int K1, int K2, const float* __restrict__ W,
                                                     const float* __restrict__ bias, float* __restrict__ out,
                                                     int M, int relu_in){
  __shared__ float Ws[128*NC];
  __shared__ float bs[NC];
  int K = K1 + K2;
  for (int i = threadIdx.x; i < K*NC; i += 256) Ws[i] = W[i];
  if (threadIdx.x < NC) bs[threadIdx.x] = bias[threadIdx.x];
  __syncthreads();
  int row = blockIdx.x*256 + threadIdx.x;
  if (row >= M) return;
  float acc[NC];
  #pragma unroll
  for (int n = 0; n < NC; ++n) acc[n] = bs[n];
  const float* a = A1 + (size_t)row*K1;
  for (int k = 0; k < K1; ++k){
    float av = a[k];
    if (relu_in) av = fmaxf(av, 0.f);
    #pragma unroll
    for (int n = 0; n < NC; ++n) acc[n] += av*Ws[k*NC + n];
  }
  if (A2){
    const float* a2 = A2 + (size_t)row*K2;
    for (int k = 0; k < K2; ++k){
      float av = a2[k];
      if (relu_in) av = fmaxf(av, 0.f);
      #pragma unroll
      for (int n = 0; n < NC; ++n) acc[n] += av*Ws[(K1 + k)*NC + n];
    }
  }
  #pragma unroll
  for (int n = 0; n < NC; ++n) out[(size_t)row*NC + n] = acc[n];
}

// ---------------- alpha reduction ----------------
__global__ __launch_bounds__(1024) void alpha_kernel(const float* __restrict__ base, const float* __restrict__ gate,
                                                     const float* __restrict__ y, const int* __restrict__ index,
                                                     float* __restrict__ alpha_out){
  __shared__ float r1[1024], r2[1024];
  int tid = threadIdx.x;
  float s1 = 0.f, sall = 0.f;
  for (int i = tid; i < NIDX*NC; i += 1024){
    int ii = i / NC, n = i - ii*NC;
    int r = index[ii];
    float yv = y[(size_t)r*NC + n];
    float b = base[(size_t)r*NC + n];
    float g = gate[(size_t)r*NC + n];
    float te = expf(-b*yv);
    sall += te;
    if (g*yv >= 0.f) s1 += te;
  }
  r1[tid] = s1; r2[tid] = sall;
  __syncthreads();
  for (int off = 512; off > 0; off >>= 1){
    if (tid < off){ r1[tid] += r1[tid+off]; r2[tid] += r2[tid+off]; }
    __syncthreads();
  }
  if (tid == 0){
    float s2 = r2[0] - r1[0];
    alpha_out[0] = 0.5f*logf(s2/r1[0]);
  }
}

__global__ void axpy_kernel(const float* __restrict__ a, const float* __restrict__ b,
                            const float* __restrict__ alpha, float* __restrict__ out, int n){
  int i = blockIdx.x*blockDim.x + threadIdx.x;
  if (i < n) out[i] = a[i] + alpha[0]*b[i];
}

// ---------------- host ----------------
extern "C" void kernel_launch(void* const* d_in, const int* in_sizes, int n_in,
                              void* d_out, int out_size, void* d_ws, size_t ws_size,
                              hipStream_t stream){
  const float* x     = (const float*)d_in[0];
  const float* y     = (const float*)d_in[1];
  const int*   index = (const int*)d_in[2];
  const int*   a1r = (const int*)d_in[3];  const int* a1c = (const int*)d_in[4];  const float* a1v = (const float*)d_in[5];
  const int*   a3r = (const int*)d_in[9];  const int* a3c = (const int*)d_in[10]; const float* a3v = (const float*)d_in[11];
  const int*   a4r = (const int*)d_in[12]; const int* a4c = (const int*)d_in[13]; const float* a4v = (const float*)d_in[14];
  const int*   a5r = (const int*)d_in[15]; const int* a5c = (const int*)d_in[16]; const float* a5v = (const float*)d_in[17];
  const float* w1  = (const float*)d_in[18]; const float* b1  = (const float*)d_in[19];
  const float* w2  = (const float*)d_in[20]; const float* b2  = (const float*)d_in[21];
  const float* w3  = (const float*)d_in[22]; const float* b3  = (const float*)d_in[23];
  const float* w4  = (const float*)d_in[24]; const float* b4  = (const float*)d_in[25];
  const float* w5  = (const float*)d_in[26]; const float* b5  = (const float*)d_in[27];
  const float* w6  = (const float*)d_in[28]; const float* b6  = (const float*)d_in[29];
  const float* w10 = (const float*)d_in[30]; const float* b10 = (const float*)d_in[31];
  const float* w11 = (const float*)d_in[32]; const float* b11 = (const float*)d_in[33];
  const float* w12 = (const float*)d_in[34]; const float* b12 = (const float*)d_in[35];
  const float* d1w = (const float*)d_in[36]; const float* d1b = (const float*)d_in[37];
  const float* d2w = (const float*)d_in[38]; const float* d2b = (const float*)d_in[39];
  const float* d3w = (const float*)d_in[40]; const float* d3b = (const float*)d_in[41];
  const float* d4w = (const float*)d_in[42]; const float* d4b = (const float*)d_in[43];
  const float* sw  = (const float*)d_in[44]; const float* sb  = (const float*)d_in[45];
  float* out = (float*)d_out;

  // ---- carve workspace; optional fused-S buffers LAST with gate ----
  char* p = (char*)d_ws;
  auto carve = [&](size_t bytes) -> char* {
    char* q = p;
    p += (bytes + 255) & ~size_t(255);
    return q;
  };
  float* S1   = (float*)carve((size_t)NN*D1*4);
  float* SB   = (float*)carve((size_t)NN*D2*4);
  float* H1b  = (float*)carve((size_t)NN*D1*4);
  float* H2b  = (float*)carve((size_t)NN*D2*4);
  float* XB   = (float*)carve((size_t)NN*D3*4);
  float* X2   = (float*)carve((size_t)NN*D3*4);
  float* X3   = (float*)carve((size_t)NN*D3*4);
  float* X1D  = (float*)carve((size_t)NN*NC*4);
  float* X4D  = (float*)carve((size_t)NN*NC*4);
  float* SIM  = (float*)carve((size_t)NN*NC*4);
  float* ALPHA= (float*)carve(256);
  int*   ROWP = (int*)carve((size_t)(NN+1)*4);
  int*   FILL = (int*)carve((size_t)NN*4);
  int*   CNT  = (int*)carve((size_t)NN*4);
  int*   CHUNK= (int*)carve((size_t)NN*4);
  int*   BSUM = (int*)carve(256*4);
  // split-bf16 weight planes, transposed to [N][Kp]
  const int KP1 = 512, KP2 = 128, KP3 = 64;
  unsigned short* W1H  = (unsigned short*)carve((size_t)D1*KP1*2);
  unsigned short* W1L  = (unsigned short*)carve((size_t)D1*KP1*2);
  unsigned short* W4H  = (unsigned short*)carve((size_t)D1*KP1*2);
  unsigned short* W4L  = (unsigned short*)carve((size_t)D1*KP1*2);
  unsigned short* W10H = (unsigned short*)carve((size_t)D1*KP1*2);
  unsigned short* W10L = (unsigned short*)carve((size_t)D1*KP1*2);
  unsigned short* W2H  = (unsigned short*)carve((size_t)D2*KP2*2);
  unsigned short* W2L  = (unsigned short*)carve((size_t)D2*KP2*2);
  unsigned short* W5H  = (unsigned short*)carve((size_t)D2*KP2*2);
  unsigned short* W5L  = (unsigned short*)carve((size_t)D2*KP2*2);
  unsigned short* W11H = (unsigned short*)carve((size_t)D2*KP2*2);
  unsigned short* W11L = (unsigned short*)carve((size_t)D2*KP2*2);
  unsigned short* W3H  = (unsigned short*)carve((size_t)D3*KP3*2);
  unsigned short* W3L  = (unsigned short*)carve((size_t)D3*KP3*2);
  unsigned short* W6H  = (unsigned short*)carve((size_t)D3*KP3*2);
  unsigned short* W6L  = (unsigned short*)carve((size_t)D3*KP3*2);
  unsigned short* W12H = (unsigned short*)carve((size_t)D3*KP3*2);
  unsigned short* W12L = (unsigned short*)carve((size_t)D3*KP3*2);
  int2*  ECV  = (int2*)carve((size_t)EE*8);
  // optional (fused layer-1 GEMM) buffers:
  float* S4   = (float*)carve((size_t)NN*D1*4);
  float* S10  = (float*)carve((size_t)NN*D1*4);
  bool fused = ((size_t)(p - (char*)d_ws) <= ws_size);
  if (!fused){ S4 = S1; S10 = S1; }
  (void)n_in; (void)in_sizes; (void)out_size;

  float* OUT_X2D = out;
  float* OUT_X3D = out + (size_t)NN*NC;
  float* OUT_P2  = out + (size_t)2*NN*NC;

  const int NB_SCAN = (NN + 255)/256;
  auto build_csr = [&](const int* r, const int* c, const float* v){
    (void)hipMemsetAsync(CNT, 0, (size_t)NN*4, stream);
    hist_kernel<<<(EE+255)/256, 256, 0, stream>>>(r, CNT, EE);
    scan1_kernel<<<NB_SCAN, 256, 0, stream>>>(CNT, CHUNK, BSUM, NN);
    scan2_kernel<<<1, 256, 0, stream>>>(BSUM, NB_SCAN);
    scan3_kernel<<<NB_SCAN, 256, 0, stream>>>(CHUNK, BSUM, ROWP, FILL, NN, EE);
    scatter_kernel<<<(EE+255)/256, 256, 0, stream>>>(r, c, v, FILL, ECV, EE);
  };

  // ---- weight prep (independent of everything else) ----
  wtc3_kernel<<<dim3(D1,3), 256, 0, stream>>>(w1, w4, w10, W1H,W1L, W4H,W4L, W10H,W10L, KF, D1, KP1);
  wtc3_kernel<<<dim3(D2,3), 256, 0, stream>>>(w2, w5, w11, W2H,W2L, W5H,W5L, W11H,W11L, D1, D2, KP2);
  wtc3_kernel<<<dim3(D3,3), 256, 0, stream>>>(w3, w6, w12, W3H,W3L, W6H,W6L, W12H,W12L, D2, D3, KP3);

  const int NB128 = (NN + 127)/128;  // 391
  if (fused){
    mfma_gemm_kernel<128><<<3*NB128, 256, 0, stream>>>(x, W1H,W1L, W4H,W4L, W10H,W10L,
                                                       S1, S4, S10, NN, KF, KP1, 3);
  }

  auto run_branch = [&](const int* ar, const int* ac, const float* av, float* S_in,
                        const unsigned short* BhA, const unsigned short* BlA,
                        const float* ba,
                        const unsigned short* Bh2, const unsigned short* Bl2, const float* bb,
                        const unsigned short* Bh3, const unsigned short* Bl3, const float* bc,
                        const float* dW, const float* db,
                        float* xout, float* dout, bool need_gemm1){
    build_csr(ar, ac, av);
    if (!fused && need_gemm1){
      mfma_gemm_kernel<128><<<NB128, 256, 0, stream>>>(x, BhA,BlA, BhA,BlA, BhA,BlA,
                                                       S_in, S_in, S_in, NN, KF, KP1, 1);
    }
    spmm_kernel<128,1><<<(NN+3)/4, 256, 0, stream>>>(ROWP, ECV, S_in, ba, H1b);
    mfma_gemm_kernel<64><<<NB128, 256, 0, stream>>>(H1b, Bh2,Bl2, Bh2,Bl2, Bh2,Bl2,
                                                    SB, SB, SB, NN, D1, KP2, 1);
    spmm_kernel<64,1><<<(NN+3)/4, 256, 0, stream>>>(ROWP, ECV, SB, bb, H2b);
    mfma_gemm_kernel<64><<<NB128, 256, 0, stream>>>(H2b, Bh3,Bl3, Bh3,Bl3, Bh3,Bl3,
                                                    SB, SB, SB, NN, D2, KP3, 1);
    spmm_kernel<64,0><<<(NN+3)/4, 256, 0, stream>>>(ROWP, ECV, SB, bc, xout);
    dense7_kernel<<<(NN+255)/256, 256, 0, stream>>>(xout, nullptr, D3, 0, dW, db, dout, NN, 1);
  };

  // x1: adjacency a5, weights w1-w3 (S1 = x@w1)
  run_branch(a5r, a5c, a5v, S1,  W1H,W1L,  b1, W2H,W2L, b2, W3H,W3L, b3, d1w, d1b, XB, X1D, true);
  // x2: adjacency a4, weights w4-w6 (S4 = x@w4)
  run_branch(a4r, a4c, a4v, S4,  W4H,W4L,  b4, W5H,W5L, b5, W6H,W6L, b6, d2w, d2b, X2, OUT_X2D, true);
  // x3: adjacency a3, same weights w4-w6 -> S4 still valid
  run_branch(a3r, a3c, a3v, S4,  W4H,W4L,  b4, W5H,W5L, b5, W6H,W6L, b6, d3w, d3b, X3, OUT_X3D, false);
  // x4: adjacency a1, weights w10-w12 (S10 = x@w10)
  run_branch(a1r, a1c, a1v, S10, W10H,W10L, b10, W11H,W11L, b11, W12H,W12L, b12, d4w, d4b, XB, X4D, true);

  // sim = [x2 | x3] @ sw + sb
  dense7_kernel<<<(NN+255)/256, 256, 0, stream>>>(X2, X3, D3, D3, sw, sb, SIM, NN, 0);

  // part1 = x4d + alpha(x4d, sim)*sim
  alpha_kernel<<<1, 1024, 0, stream>>>(X4D, SIM, y, index, ALPHA);
  axpy_kernel<<<((NN*NC)+255)/256, 256, 0, stream>>>(X4D, SIM, ALPHA, OUT_P2, NN*NC);
  // part2 = part1 + alpha(part1, x1d)*x1d
  alpha_kernel<<<1, 1024, 0, stream>>>(OUT_P2, X1D, y, index, ALPHA+1);
  axpy_kernel<<<((NN*NC)+255)/256, 256, 0, stream>>>(OUT_P2, X1D, ALPHA+1, OUT_P2, NN*NC);
}

// Round 6
// 1159.737 us; speedup vs baseline: 2.0796x; 1.2216x over previous
//
#include <hip/hip_runtime.h>
#include <hip/hip_fp16.h>
#include <cstddef>

#define NN 50000      // nodes
#define EE 800000     // edges per adjacency
#define KF 500        // NFEAT
#define D1 128        // H2
#define D2 64         // H3
#define D3 64         // H4
#define NC 7          // classes
#define NIDX 5000     // index size
#define NTK 16        // ceil(KF/32) k-tiles for layer-1
#define NB 391        // ceil(NN/128) row-blocks

typedef __attribute__((ext_vector_type(8))) short bf16x8;
typedef __attribute__((ext_vector_type(4))) float f32x4;
typedef __attribute__((ext_vector_type(4))) unsigned short u16x4;
typedef __attribute__((ext_vector_type(8))) unsigned short u16x8;

__device__ __forceinline__ unsigned short bfh(float f){
  unsigned u = __float_as_uint(f);
  u += 0x7FFFu + ((u >> 16) & 1u);
  return (unsigned short)(u >> 16);
}
__device__ __forceinline__ void bfsplit(float a, unsigned short& h, unsigned short& l){
  h = bfh(a);
  float r = a - __uint_as_float(((unsigned)h) << 16);
  l = bfh(r);
}

// async 1KB global->LDS stage: per-lane 16B, linear LDS dest
__device__ __forceinline__ void stage1k(const unsigned short* g, unsigned short* l, int lane){
  __builtin_amdgcn_global_load_lds((const __attribute__((address_space(1))) void*)(g + lane*8),
                                   (__attribute__((address_space(3))) void*)l, 16, 0, 0);
}

// ---------------- batched CSR build (adj = blockIdx.y / blockIdx.x for scan2) ----------------
__global__ void hist4_kernel(const int* __restrict__ r0, const int* __restrict__ r1,
                             const int* __restrict__ r2, const int* __restrict__ r3,
                             int* __restrict__ cnt4){
  int adj = blockIdx.y;
  const int* r = (adj==0)?r0:(adj==1)?r1:(adj==2)?r2:r3;
  int* cnt = cnt4 + (size_t)adj*NN;
  int i = blockIdx.x*256 + threadIdx.x;
  if (i < EE) atomicAdd(&cnt[r[i]], 1);
}
__global__ __launch_bounds__(256) void scan1_kernel(const int* __restrict__ cnt4, int* __restrict__ chunk4,
                                                    int* __restrict__ bsum4){
  int adj = blockIdx.y;
  const int* cnt = cnt4 + (size_t)adj*NN;
  int* chunk = chunk4 + (size_t)adj*NN;
  int* bsum = bsum4 + adj*256;
  __shared__ int buf[256];
  int tid = threadIdx.x;
  int i = blockIdx.x*256 + tid;
  int v = (i < NN) ? cnt[i] : 0;
  buf[tid] = v;
  __syncthreads();
  for (int off = 1; off < 256; off <<= 1){
    int t = (tid >= off) ? buf[tid - off] : 0;
    __syncthreads();
    buf[tid] += t;
    __syncthreads();
  }
  if (i < NN) chunk[i] = buf[tid] - v;
  if (tid == 255) bsum[blockIdx.x] = buf[255];
}
__global__ __launch_bounds__(256) void scan2_kernel(int* __restrict__ bsum4, int nb){
  int* bsum = bsum4 + blockIdx.x*256;
  __shared__ int buf[256];
  int tid = threadIdx.x;
  int v = (tid < nb) ? bsum[tid] : 0;
  buf[tid] = v;
  __syncthreads();
  for (int off = 1; off < 256; off <<= 1){
    int t = (tid >= off) ? buf[tid - off] : 0;
    __syncthreads();
    buf[tid] += t;
    __syncthreads();
  }
  if (tid < nb) bsum[tid] = buf[tid] - v;
}
__global__ void scan3_kernel(const int* __restrict__ chunk4, const int* __restrict__ bsum4,
                             int* __restrict__ rowp4, int* __restrict__ fill4){
  int adj = blockIdx.y;
  const int* chunk = chunk4 + (size_t)adj*NN;
  const int* bsum = bsum4 + adj*256;
  int* rowp = rowp4 + (size_t)adj*(NN+1);
  int* fill = fill4 + (size_t)adj*NN;
  int i = blockIdx.x*256 + threadIdx.x;
  if (i < NN){
    int e = chunk[i] + bsum[blockIdx.x];
    rowp[i] = e; fill[i] = e;
  }
  if (i == 0) rowp[NN] = EE;
}
__global__ void scatter4_kernel(const int* __restrict__ r0, const int* __restrict__ c0, const float* __restrict__ v0,
                                const int* __restrict__ r1, const int* __restrict__ c1, const float* __restrict__ v1,
                                const int* __restrict__ r2, const int* __restrict__ c2, const float* __restrict__ v2,
                                const int* __restrict__ r3, const int* __restrict__ c3, const float* __restrict__ v3,
                                int* __restrict__ fill4, int2* __restrict__ ecv4){
  int adj = blockIdx.y;
  const int* r = (adj==0)?r0:(adj==1)?r1:(adj==2)?r2:r3;
  const int* c = (adj==0)?c0:(adj==1)?c1:(adj==2)?c2:c3;
  const float* v = (adj==0)?v0:(adj==1)?v1:(adj==2)?v2:v3;
  int* fill = fill4 + (size_t)adj*NN;
  int2* ecv = ecv4 + (size_t)adj*EE;
  int i = blockIdx.x*256 + threadIdx.x;
  if (i < EE){
    int p = atomicAdd(&fill[r[i]], 1);
    ecv[p] = make_int2(c[i], __float_as_int(v[i]));
  }
}

// ---------------- x -> fragment-tiled split-bf16 planes ----------------
// tile = (rb, ks), 128 rows x 32 k; elem order: f*512 + l*8 + kr where
// row = f*16 + (l&15), k = (l>>4)*8 + kr  (matches MFMA A-frag lane order)
__global__ __launch_bounds__(256) void convx_kernel(const float* __restrict__ A,
                                                    unsigned short* __restrict__ Xh,
                                                    unsigned short* __restrict__ Xl,
                                                    int M, int K){
  int rb = blockIdx.x / NTK, ks = blockIdx.x % NTK;
  __shared__ float T[128][33];
  int t = threadIdx.x;
  int tr = t >> 3, tk = (t & 7) * 4;
  #pragma unroll
  for (int p = 0; p < 4; ++p){
    int r = tr + p*32;
    int gr = rb*128 + r, gk = ks*32 + tk;
    float4 v = make_float4(0.f,0.f,0.f,0.f);
    if (gr < M && gk + 4 <= K) v = *reinterpret_cast<const float4*>(&A[(size_t)gr*K + gk]);
    T[r][tk] = v.x; T[r][tk+1] = v.y; T[r][tk+2] = v.z; T[r][tk+3] = v.w;
  }
  __syncthreads();
  size_t tb = (size_t)blockIdx.x * 4096;
  unsigned short hh[16], ll[16];
  #pragma unroll
  for (int i = 0; i < 16; ++i){
    int e = t*16 + i;
    int f = e >> 9, rem = e & 511, l = rem >> 3, kr = rem & 7;
    int row = f*16 + (l & 15), k = ((l >> 4) << 3) + kr;
    bfsplit(T[row][k], hh[i], ll[i]);
  }
  *reinterpret_cast<u16x8*>(&Xh[tb + t*16])     = *reinterpret_cast<u16x8*>(&hh[0]);
  *reinterpret_cast<u16x8*>(&Xh[tb + t*16 + 8]) = *reinterpret_cast<u16x8*>(&hh[8]);
  *reinterpret_cast<u16x8*>(&Xl[tb + t*16])     = *reinterpret_cast<u16x8*>(&ll[0]);
  *reinterpret_cast<u16x8*>(&Xl[tb + t*16 + 8]) = *reinterpret_cast<u16x8*>(&ll[8]);
}

// ---------------- big W -> fragment-tiled split planes (col plays "row" role) ----------------
__global__ __launch_bounds__(256) void wtcf_kernel(const float* __restrict__ W0, const float* __restrict__ W1,
                                                   const float* __restrict__ W2,
                                                   unsigned short* __restrict__ H0, unsigned short* __restrict__ L0,
                                                   unsigned short* __restrict__ H1, unsigned short* __restrict__ L1,
                                                   unsigned short* __restrict__ H2, unsigned short* __restrict__ L2,
                                                   int K){
  int which = blockIdx.y, ks = blockIdx.x;
  const float* W = (which==0)?W0:(which==1)?W1:W2;
  unsigned short* H = (which==0)?H0:(which==1)?H1:H2;
  unsigned short* L = (which==0)?L0:(which==1)?L1:L2;
  int t = threadIdx.x;
  size_t tb = (size_t)ks * 4096;
  unsigned short hh[16], ll[16];
  #pragma unroll
  for (int i = 0; i < 16; ++i){
    int e = t*16 + i;
    int f = e >> 9, rem = e & 511, l = rem >> 3, kr = rem & 7;
    int col = f*16 + (l & 15), k = ks*32 + ((l >> 4) << 3) + kr;
    float v = (k < K) ? W[(size_t)k*D1 + col] : 0.f;
    bfsplit(v, hh[i], ll[i]);
  }
  *reinterpret_cast<u16x8*>(&H[tb + t*16])     = *reinterpret_cast<u16x8*>(&hh[0]);
  *reinterpret_cast<u16x8*>(&H[tb + t*16 + 8]) = *reinterpret_cast<u16x8*>(&hh[8]);
  *reinterpret_cast<u16x8*>(&L[tb + t*16])     = *reinterpret_cast<u16x8*>(&ll[0]);
  *reinterpret_cast<u16x8*>(&L[tb + t*16 + 8]) = *reinterpret_cast<u16x8*>(&ll[8]);
}

// ---------------- layer-1 fused 3x GEMM: pre-tiled A/B, DMA staging, conflict-free frags ----------------
__global__ __launch_bounds__(256) void gemm3f_kernel(
    const unsigned short* __restrict__ Xh, const unsigned short* __restrict__ Xl,
    const unsigned short* __restrict__ B0h, const unsigned short* __restrict__ B0l,
    const unsigned short* __restrict__ B1h, const unsigned short* __restrict__ B1l,
    const unsigned short* __restrict__ B2h, const unsigned short* __restrict__ B2l,
    __half* __restrict__ C0, __half* __restrict__ C1, __half* __restrict__ C2, int M){
  __shared__ unsigned short Ah[4096], Al[4096], Bh[4096], Bl[4096];
  int which = blockIdx.x % 3;
  int rb    = blockIdx.x / 3;
  const unsigned short* BhP = (which==0)?B0h:(which==1)?B1h:B2h;
  const unsigned short* BlP = (which==0)?B0l:(which==1)?B1l:B2l;
  __half* C = (which==0)?C0:(which==1)?C1:C2;

  int tid = threadIdx.x;
  int lane = tid & 63, wid = tid >> 6;
  int wr = wid >> 1, wc = wid & 1;

  f32x4 acc[4][4];
  #pragma unroll
  for (int i = 0; i < 4; ++i)
    #pragma unroll
    for (int j = 0; j < 4; ++j) acc[i][j] = (f32x4){0.f,0.f,0.f,0.f};

  for (int ks = 0; ks < NTK; ++ks){
    size_t atb = ((size_t)(rb*NTK + ks)) * 4096;
    size_t btb = (size_t)ks * 4096;
    const unsigned short* gsrc;
    unsigned short* ldst;
    if (wid == 0){ gsrc = Xh + atb; ldst = Ah; }
    else if (wid == 1){ gsrc = Xl + atb; ldst = Al; }
    else if (wid == 2){ gsrc = BhP + btb; ldst = Bh; }
    else { gsrc = BlP + btb; ldst = Bl; }
    #pragma unroll
    for (int c = 0; c < 8; ++c) stage1k(gsrc + c*512, ldst + c*512, lane);
    __syncthreads();

    bf16x8 ah[4], al[4], bh[4], bl[4];
    int fo = lane * 8;
    #pragma unroll
    for (int mi = 0; mi < 4; ++mi){
      ah[mi] = *reinterpret_cast<const bf16x8*>(&Ah[(wr*4 + mi)*512 + fo]);
      al[mi] = *reinterpret_cast<const bf16x8*>(&Al[(wr*4 + mi)*512 + fo]);
    }
    #pragma unroll
    for (int ni = 0; ni < 4; ++ni){
      bh[ni] = *reinterpret_cast<const bf16x8*>(&Bh[(wc*4 + ni)*512 + fo]);
      bl[ni] = *reinterpret_cast<const bf16x8*>(&Bl[(wc*4 + ni)*512 + fo]);
    }
    #pragma unroll
    for (int mi = 0; mi < 4; ++mi)
      #pragma unroll
      for (int ni = 0; ni < 4; ++ni){
        acc[mi][ni] = __builtin_amdgcn_mfma_f32_16x16x32_bf16(ah[mi], bh[ni], acc[mi][ni], 0, 0, 0);
        acc[mi][ni] = __builtin_amdgcn_mfma_f32_16x16x32_bf16(ah[mi], bl[ni], acc[mi][ni], 0, 0, 0);
        acc[mi][ni] = __builtin_amdgcn_mfma_f32_16x16x32_bf16(al[mi], bh[ni], acc[mi][ni], 0, 0, 0);
      }
    __syncthreads();
  }
  #pragma unroll
  for (int mi = 0; mi < 4; ++mi){
    int rowb = rb*128 + wr*64 + mi*16 + (lane >> 4)*4;
    #pragma unroll
    for (int ni = 0; ni < 4; ++ni){
      int col = wc*64 + ni*16 + (lane & 15);
      #pragma unroll
      for (int i = 0; i < 4; ++i){
        int r = rowb + i;
        if (r < M) C[(size_t)r*128 + col] = __float2half(acc[mi][ni][i]);
      }
    }
  }
}

// ---------------- old-style weight transpose + split: W[K][N] -> [N][Kp] planes ----------------
__global__ __launch_bounds__(256) void wtc3_kernel(
    const float* __restrict__ W0, const float* __restrict__ W1, const float* __restrict__ W2,
    unsigned short* __restrict__ H0, unsigned short* __restrict__ L0,
    unsigned short* __restrict__ H1, unsigned short* __restrict__ L1,
    unsigned short* __restrict__ H2, unsigned short* __restrict__ L2,
    int K, int N, int Kp){
  int w = blockIdx.y;
  const float* W = (w==0)?W0:(w==1)?W1:W2;
  unsigned short* H = (w==0)?H0:(w==1)?H1:H2;
  unsigned short* L = (w==0)?L0:(w==1)?L1:L2;
  int n = blockIdx.x;
  for (int k = threadIdx.x; k < Kp; k += 256){
    float v = (k < K) ? W[(size_t)k*N + n] : 0.f;
    unsigned short h, l; bfsplit(v, h, l);
    H[(size_t)n*Kp + k] = h;
    L[(size_t)n*Kp + k] = l;
  }
}

// ---------------- split-bf16 MFMA GEMM (fp32 A staged+converted in-kernel) ----------------
template<int BN, int HOUT>
__global__ __launch_bounds__(256) void mfma_gemm_kernel(
    const float* __restrict__ A,
    const unsigned short* __restrict__ Bh0, const unsigned short* __restrict__ Bl0,
    const unsigned short* __restrict__ Bh1, const unsigned short* __restrict__ Bl1,
    const unsigned short* __restrict__ Bh2, const unsigned short* __restrict__ Bl2,
    void* __restrict__ C0, void* __restrict__ C1, void* __restrict__ C2,
    int M, int K, int Kp, int ngemm){
  constexpr int LD = 40;
  constexpr int NFR = BN/32;
  __shared__ __align__(16) unsigned short Ah[128*LD], Al[128*LD];
  __shared__ __align__(16) unsigned short Bhs[BN*LD], Bls[BN*LD];

  int which = blockIdx.x % ngemm;
  int rb    = blockIdx.x / ngemm;
  const unsigned short* Bh = (which==0)?Bh0:(which==1)?Bh1:Bh2;
  const unsigned short* Bl = (which==0)?Bl0:(which==1)?Bl1:Bl2;
  void* C = (which==0)?C0:(which==1)?C1:C2;

  int tid = threadIdx.x;
  int lane = tid & 63, wid = tid >> 6;
  int wr = wid >> 1, wc = wid & 1;
  int row0 = rb*128;

  f32x4 acc[4][NFR];
  #pragma unroll
  for (int i = 0; i < 4; ++i)
    #pragma unroll
    for (int j = 0; j < NFR; ++j) acc[i][j] = (f32x4){0.f,0.f,0.f,0.f};

  int sa_m = tid >> 3, sa_j = tid & 7;
  int sb_n = tid >> 2, sb_j = tid & 3;
  int fr_off = (lane & 15)*LD + (lane >> 4)*8;

  for (int k0 = 0; k0 < K; k0 += 32){
    #pragma unroll
    for (int p = 0; p < 4; ++p){
      int m = sa_m + p*32;
      int gr = row0 + m, gk = k0 + sa_j*4;
      float4 v = make_float4(0.f,0.f,0.f,0.f);
      if (gr < M && gk + 4 <= K) v = *reinterpret_cast<const float4*>(&A[(size_t)gr*K + gk]);
      unsigned short h0,h1,h2,h3,l0,l1,l2,l3;
      bfsplit(v.x,h0,l0); bfsplit(v.y,h1,l1); bfsplit(v.z,h2,l2); bfsplit(v.w,h3,l3);
      u16x4 hv = {h0,h1,h2,h3}, lv = {l0,l1,l2,l3};
      *reinterpret_cast<u16x4*>(&Ah[m*LD + sa_j*4]) = hv;
      *reinterpret_cast<u16x4*>(&Al[m*LD + sa_j*4]) = lv;
    }
    #pragma unroll
    for (int p = 0; p < BN/64; ++p){
      int n = sb_n + p*64;
      int gk = k0 + sb_j*8;
      u16x8 hv = *reinterpret_cast<const u16x8*>(&Bh[(size_t)n*Kp + gk]);
      u16x8 lv = *reinterpret_cast<const u16x8*>(&Bl[(size_t)n*Kp + gk]);
      *reinterpret_cast<u16x8*>(&Bhs[n*LD + sb_j*8]) = hv;
      *reinterpret_cast<u16x8*>(&Bls[n*LD + sb_j*8]) = lv;
    }
    __syncthreads();
    bf16x8 ah[4], al[4], bh[NFR], bl[NFR];
    #pragma unroll
    for (int mi = 0; mi < 4; ++mi){
      int off = (wr*64 + mi*16)*LD + fr_off;
      ah[mi] = *reinterpret_cast<const bf16x8*>(&Ah[off]);
      al[mi] = *reinterpret_cast<const bf16x8*>(&Al[off]);
    }
    #pragma unroll
    for (int ni = 0; ni < NFR; ++ni){
      int off = (wc*(BN/2) + ni*16)*LD + fr_off;
      bh[ni] = *reinterpret_cast<const bf16x8*>(&Bhs[off]);
      bl[ni] = *reinterpret_cast<const bf16x8*>(&Bls[off]);
    }
    #pragma unroll
    for (int mi = 0; mi < 4; ++mi)
      #pragma unroll
      for (int ni = 0; ni < NFR; ++ni){
        acc[mi][ni] = __builtin_amdgcn_mfma_f32_16x16x32_bf16(ah[mi], bh[ni], acc[mi][ni], 0, 0, 0);
        acc[mi][ni] = __builtin_amdgcn_mfma_f32_16x16x32_bf16(ah[mi], bl[ni], acc[mi][ni], 0, 0, 0);
        acc[mi][ni] = __builtin_amdgcn_mfma_f32_16x16x32_bf16(al[mi], bh[ni], acc[mi][ni], 0, 0, 0);
      }
    __syncthreads();
  }
  #pragma unroll
  for (int mi = 0; mi < 4; ++mi){
    int rowb = row0 + wr*64 + mi*16 + (lane >> 4)*4;
    #pragma unroll
    for (int ni = 0; ni < NFR; ++ni){
      int col = wc*(BN/2) + ni*16 + (lane & 15);
      #pragma unroll
      for (int i = 0; i < 4; ++i){
        int r = rowb + i;
        if (r < M){
          if (HOUT) ((__half*)C)[(size_t)r*BN + col] = __float2half(acc[mi][ni][i]);
          else      ((float*)C)[(size_t)r*BN + col] = acc[mi][ni][i];
        }
      }
    }
  }
}

// ---------------- gather SpMM (ST = float or __half) ----------------
__device__ __forceinline__ float2 ld2f(const float* p, int lane){
  return ((const float2*)p)[lane];
}
__device__ __forceinline__ float2 ld2f(const __half* p, int lane){
  __half2 h = ((const __half2*)p)[lane];
  return make_float2(__low2float(h), __high2float(h));
}
__device__ __forceinline__ float ld1f(const float* p, int lane){ return p[lane]; }
__device__ __forceinline__ float ld1f(const __half* p, int lane){ return __half2float(p[lane]); }

template<int H, int RELU, typename ST>
__global__ __launch_bounds__(256) void spmm_kernel(const int* __restrict__ row_ptr, const int2* __restrict__ ecv,
                                                   const ST* __restrict__ S,
                                                   const float* __restrict__ bias, float* __restrict__ out){
  int row = blockIdx.x*4 + (threadIdx.x >> 6);
  int lane = threadIdx.x & 63;
  if (row >= NN) return;
  int p0 = row_ptr[row], p1 = row_ptr[row+1];
  float2 a2A = make_float2(0.f,0.f), a2B = make_float2(0.f,0.f);
  float a1A = 0.f, a1B = 0.f;
  for (int base = p0; base < p1; base += 64){
    int nrem = p1 - base; if (nrem > 64) nrem = 64;
    int2 ev = (lane < nrem) ? ecv[base + lane] : make_int2(0, 0);
    int i = 0;
    for (; i + 2 <= nrem; i += 2){
      int c0   = __shfl(ev.x, i);
      float v0 = __int_as_float(__shfl(ev.y, i));
      int c1   = __shfl(ev.x, i+1);
      float v1 = __int_as_float(__shfl(ev.y, i+1));
      if (H == 128){
        float2 s0 = ld2f(S + (size_t)c0*128, lane);
        float2 s1 = ld2f(S + (size_t)c1*128, lane);
        a2A.x += v0*s0.x; a2A.y += v0*s0.y;
        a2B.x += v1*s1.x; a2B.y += v1*s1.y;
      } else {
        a1A += v0 * ld1f(S + (size_t)c0*64, lane);
        a1B += v1 * ld1f(S + (size_t)c1*64, lane);
      }
    }
    if (i < nrem){
      int c0   = __shfl(ev.x, i);
      float v0 = __int_as_float(__shfl(ev.y, i));
      if (H == 128){
        float2 s0 = ld2f(S + (size_t)c0*128, lane);
        a2A.x += v0*s0.x; a2A.y += v0*s0.y;
      } else {
        a1A += v0 * ld1f(S + (size_t)c0*64, lane);
      }
    }
  }
  if (H == 128){
    float2 b = ((const float2*)bias)[lane];
    float2 acc = make_float2(a2A.x + a2B.x + b.x, a2A.y + a2B.y + b.y);
    if (RELU){ acc.x = fmaxf(acc.x, 0.f); acc.y = fmaxf(acc.y, 0.f); }
    ((float2*)(out + (size_t)row*128))[lane] = acc;
  } else {
    float acc = a1A + a1B + bias[lane];
    if (RELU) acc = fmaxf(acc, 0.f);
    out[(size_t)row*64 + lane] = acc;
  }
}

// ---------------- tall-skinny dense: out[M,7] = (relu?)([A1|A2]) @ W + b ----------------
__global__ __launch_bounds__(256) void dense7_kernel(const float* __restrict__ A1, const float* __restrict__ A2,
                                                     int K1, int K2, const float* __restrict__ W,
                                                     const float* __restrict__ bias, float* __restrict__ out,
                                                     int M, int relu_in){
  __shared__ float Ws[128*NC];
  __shared__ float bs[NC];
  int K = K1 + K2;
  for (int i = threadIdx.x; i < K*NC; i += 256) Ws[i] = W[i];
  if (threadIdx.x < NC) bs[threadIdx.x] = bias[threadIdx.x];
  __syncthreads();
  int row = blockIdx.x*256 + threadIdx.x;
  if (row >= M) return;
  float acc[NC];
  #pragma unroll
  for (int n = 0; n < NC; ++n) acc[n] = bs[n];
  const float* a = A1 + (size_t)row*K1;
  for (int k = 0; k < K1; ++k){
    float av = a[k];
    if (relu_in) av = fmaxf(av, 0.f);
    #pragma unroll
    for (int n = 0; n < NC; ++n) acc[n] += av*Ws[k*NC + n];
  }
  if (A2){
    const float* a2 = A2 + (size_t)row*K2;
    for (int k = 0; k < K2; ++k){
      float av = a2[k];
      if (relu_in) av = fmaxf(av, 0.f);
      #pragma unroll
      for (int n = 0; n < NC; ++n) acc[n] += av*Ws[(K1 + k)*NC + n];
    }
  }
  #pragma unroll
  for (int n = 0; n < NC; ++n) out[(size_t)row*NC + n] = acc[n];
}

// ---------------- alpha reduction ----------------
__global__ __launch_bounds__(1024) void alpha_kernel(const float* __restrict__ base, const float* __restrict__ gate,
                                                     const float* __restrict__ y, const int* __restrict__ index,
                                                     float* __restrict__ alpha_out){
  __shared__ float r1[1024], r2[1024];
  int tid = threadIdx.x;
  float s1 = 0.f, sall = 0.f;
  for (int i = tid; i < NIDX*NC; i += 1024){
    int ii = i / NC, n = i - ii*NC;
    int r = index[ii];
    float yv = y[(size_t)r*NC + n];
    float b = base[(size_t)r*NC + n];
    float g = gate[(size_t)r*NC + n];
    float te = expf(-b*yv);
    sall += te;
    if (g*yv >= 0.f) s1 += te;
  }
  r1[tid] = s1; r2[tid] = sall;
  __syncthreads();
  for (int off = 512; off > 0; off >>= 1){
    if (tid < off){ r1[tid] += r1[tid+off]; r2[tid] += r2[tid+off]; }
    __syncthreads();
  }
  if (tid == 0){
    float s2 = r2[0] - r1[0];
    alpha_out[0] = 0.5f*logf(s2/r1[0]);
  }
}

__global__ void axpy_kernel(const float* __restrict__ a, const float* __restrict__ b,
                            const float* __restrict__ alpha, float* __restrict__ out, int n){
  int i = blockIdx.x*blockDim.x + threadIdx.x;
  if (i < n) out[i] = a[i] + alpha[0]*b[i];
}

// ---------------- host ----------------
extern "C" void kernel_launch(void* const* d_in, const int* in_sizes, int n_in,
                              void* d_out, int out_size, void* d_ws, size_t ws_size,
                              hipStream_t stream){
  const float* x     = (const float*)d_in[0];
  const float* y     = (const float*)d_in[1];
  const int*   index = (const int*)d_in[2];
  const int*   a1r = (const int*)d_in[3];  const int* a1c = (const int*)d_in[4];  const float* a1v = (const float*)d_in[5];
  const int*   a3r = (const int*)d_in[9];  const int* a3c = (const int*)d_in[10]; const float* a3v = (const float*)d_in[11];
  const int*   a4r = (const int*)d_in[12]; const int* a4c = (const int*)d_in[13]; const float* a4v = (const float*)d_in[14];
  const int*   a5r = (const int*)d_in[15]; const int* a5c = (const int*)d_in[16]; const float* a5v = (const float*)d_in[17];
  const float* w1  = (const float*)d_in[18]; const float* b1  = (const float*)d_in[19];
  const float* w2  = (const float*)d_in[20]; const float* b2  = (const float*)d_in[21];
  const float* w3  = (const float*)d_in[22]; const float* b3  = (const float*)d_in[23];
  const float* w4  = (const float*)d_in[24]; const float* b4  = (const float*)d_in[25];
  const float* w5  = (const float*)d_in[26]; const float* b5  = (const float*)d_in[27];
  const float* w6  = (const float*)d_in[28]; const float* b6  = (const float*)d_in[29];
  const float* w10 = (const float*)d_in[30]; const float* b10 = (const float*)d_in[31];
  const float* w11 = (const float*)d_in[32]; const float* b11 = (const float*)d_in[33];
  const float* w12 = (const float*)d_in[34]; const float* b12 = (const float*)d_in[35];
  const float* d1w = (const float*)d_in[36]; const float* d1b = (const float*)d_in[37];
  const float* d2w = (const float*)d_in[38]; const float* d2b = (const float*)d_in[39];
  const float* d3w = (const float*)d_in[40]; const float* d3b = (const float*)d_in[41];
  const float* d4w = (const float*)d_in[42]; const float* d4b = (const float*)d_in[43];
  const float* sw  = (const float*)d_in[44]; const float* sb  = (const float*)d_in[45];
  float* out = (float*)d_out;
  (void)n_in; (void)in_sizes; (void)out_size;

  float* OUT_X2D = out;
  float* OUT_X3D = out + (size_t)NN*NC;
  float* OUT_P2  = out + (size_t)2*NN*NC;

  char* p = (char*)d_ws;
  auto carve = [&](size_t bytes) -> char* {
    char* q = p;
    p += (bytes + 255) & ~size_t(255);
    return q;
  };

  // ======== try NEW layout ========
  const size_t XTE = (size_t)NB*NTK*4096;   // tiled elements per plane
  unsigned short* Xh  = (unsigned short*)carve(XTE*2);
  unsigned short* Xl  = (unsigned short*)carve(XTE*2);
  const size_t BTE = (size_t)NTK*4096;
  unsigned short* B1H = (unsigned short*)carve(BTE*2); unsigned short* B1L = (unsigned short*)carve(BTE*2);
  unsigned short* B4H = (unsigned short*)carve(BTE*2); unsigned short* B4L = (unsigned short*)carve(BTE*2);
  unsigned short* B10H= (unsigned short*)carve(BTE*2); unsigned short* B10L= (unsigned short*)carve(BTE*2);
  __half* S1  = (__half*)carve((size_t)NN*D1*2);
  __half* S4  = (__half*)carve((size_t)NN*D1*2);
  __half* S10 = (__half*)carve((size_t)NN*D1*2);
  __half* SBh = (__half*)carve((size_t)NN*D2*2);
  float* H1b  = (float*)carve((size_t)NN*D1*4);
  float* H2b  = (float*)carve((size_t)NN*D2*4);
  float* XB   = (float*)carve((size_t)NN*D3*4);
  float* X2   = (float*)carve((size_t)NN*D3*4);
  float* X3   = (float*)carve((size_t)NN*D3*4);
  float* X1D  = (float*)carve((size_t)NN*NC*4);
  float* X4D  = (float*)carve((size_t)NN*NC*4);
  float* SIM  = (float*)carve((size_t)NN*NC*4);
  float* ALPHA= (float*)carve(256);
  int*   ROWP4 = (int*)carve((size_t)4*(NN+1)*4);
  int*   FILL4 = (int*)carve((size_t)4*NN*4);
  int*   CNT4  = (int*)carve((size_t)4*NN*4);
  int*   CHUNK4= (int*)carve((size_t)4*NN*4);
  int*   BSUM4 = (int*)carve(4*256*4);
  const int KP2 = 128, KP3 = 64;
  unsigned short* W2H  = (unsigned short*)carve((size_t)D2*KP2*2);
  unsigned short* W2L  = (unsigned short*)carve((size_t)D2*KP2*2);
  unsigned short* W5H  = (unsigned short*)carve((size_t)D2*KP2*2);
  unsigned short* W5L  = (unsigned short*)carve((size_t)D2*KP2*2);
  unsigned short* W11H = (unsigned short*)carve((size_t)D2*KP2*2);
  unsigned short* W11L = (unsigned short*)carve((size_t)D2*KP2*2);
  unsigned short* W3H  = (unsigned short*)carve((size_t)D3*KP3*2);
  unsigned short* W3L  = (unsigned short*)carve((size_t)D3*KP3*2);
  unsigned short* W6H  = (unsigned short*)carve((size_t)D3*KP3*2);
  unsigned short* W6L  = (unsigned short*)carve((size_t)D3*KP3*2);
  unsigned short* W12H = (unsigned short*)carve((size_t)D3*KP3*2);
  unsigned short* W12L = (unsigned short*)carve((size_t)D3*KP3*2);
  int2*  ECV4 = (int2*)carve((size_t)4*EE*8);
  bool newpath = ((size_t)(p - (char*)d_ws) <= ws_size);

  const int NB_SCAN = (NN + 255)/256;   // 196

  if (newpath){
    // weight/feature prep
    convx_kernel<<<NB*NTK, 256, 0, stream>>>(x, Xh, Xl, NN, KF);
    wtcf_kernel<<<dim3(NTK,3), 256, 0, stream>>>(w1, w4, w10, B1H,B1L, B4H,B4L, B10H,B10L, KF);
    wtc3_kernel<<<dim3(D2,3), 256, 0, stream>>>(w2, w5, w11, W2H,W2L, W5H,W5L, W11H,W11L, D1, D2, KP2);
    wtc3_kernel<<<dim3(D3,3), 256, 0, stream>>>(w3, w6, w12, W3H,W3L, W6H,W6L, W12H,W12L, D2, D3, KP3);
    // batched CSR for all 4 adjacencies; slots: 0=a5(x1), 1=a4(x2), 2=a3(x3), 3=a1(x4)
    (void)hipMemsetAsync(CNT4, 0, (size_t)4*NN*4, stream);
    hist4_kernel<<<dim3((EE+255)/256,4), 256, 0, stream>>>(a5r, a4r, a3r, a1r, CNT4);
    scan1_kernel<<<dim3(NB_SCAN,4), 256, 0, stream>>>(CNT4, CHUNK4, BSUM4);
    scan2_kernel<<<4, 256, 0, stream>>>(BSUM4, NB_SCAN);
    scan3_kernel<<<dim3(NB_SCAN,4), 256, 0, stream>>>(CHUNK4, BSUM4, ROWP4, FILL4);
    scatter4_kernel<<<dim3((EE+255)/256,4), 256, 0, stream>>>(a5r,a5c,a5v, a4r,a4c,a4v, a3r,a3c,a3v, a1r,a1c,a1v,
                                                              FILL4, ECV4);
    // fused layer-1 GEMMs
    gemm3f_kernel<<<3*NB, 256, 0, stream>>>(Xh, Xl, B1H,B1L, B4H,B4L, B10H,B10L, S1, S4, S10, NN);

    auto run_branch = [&](int slot, const __half* S_in,
                          const float* ba,
                          const unsigned short* Bh2, const unsigned short* Bl2, const float* bb,
                          const unsigned short* Bh3, const unsigned short* Bl3, const float* bc,
                          const float* dW, const float* db,
                          float* xout, float* dout){
      const int* rowp = ROWP4 + (size_t)slot*(NN+1);
      const int2* ecv = ECV4 + (size_t)slot*EE;
      spmm_kernel<128,1,__half><<<(NN+3)/4, 256, 0, stream>>>(rowp, ecv, S_in, ba, H1b);
      mfma_gemm_kernel<64,1><<<NB, 256, 0, stream>>>(H1b, Bh2,Bl2, Bh2,Bl2, Bh2,Bl2,
                                                     SBh, SBh, SBh, NN, D1, KP2, 1);
      spmm_kernel<64,1,__half><<<(NN+3)/4, 256, 0, stream>>>(rowp, ecv, SBh, bb, H2b);
      mfma_gemm_kernel<64,1><<<NB, 256, 0, stream>>>(H2b, Bh3,Bl3, Bh3,Bl3, Bh3,Bl3,
                                                     SBh, SBh, SBh, NN, D2, KP3, 1);
      spmm_kernel<64,0,__half><<<(NN+3)/4, 256, 0, stream>>>(rowp, ecv, SBh, bc, xout);
      dense7_kernel<<<(NN+255)/256, 256, 0, stream>>>(xout, nullptr, D3, 0, dW, db, dout, NN, 1);
    };

    run_branch(0, S1,  b1, W2H,W2L, b2, W3H,W3L, b3, d1w, d1b, XB, X1D);
    run_branch(1, S4,  b4, W5H,W5L, b5, W6H,W6L, b6, d2w, d2b, X2, OUT_X2D);
    run_branch(2, S4,  b4, W5H,W5L, b5, W6H,W6L, b6, d3w, d3b, X3, OUT_X3D);
    run_branch(3, S10, b10, W11H,W11L, b11, W12H,W12L, b12, d4w, d4b, XB, X4D);
  } else {
    // ======== fallback: round-5 proven structure (fp32 S, in-kernel staging) ========
    p = (char*)d_ws;
    float* fS1   = (float*)carve((size_t)NN*D1*4);
    float* fSB   = (float*)carve((size_t)NN*D2*4);
    H1b  = (float*)carve((size_t)NN*D1*4);
    H2b  = (float*)carve((size_t)NN*D2*4);
    XB   = (float*)carve((size_t)NN*D3*4);
    X2   = (float*)carve((size_t)NN*D3*4);
    X3   = (float*)carve((size_t)NN*D3*4);
    X1D  = (float*)carve((size_t)NN*NC*4);
    X4D  = (float*)carve((size_t)NN*NC*4);
    SIM  = (float*)carve((size_t)NN*NC*4);
    ALPHA= (float*)carve(256);
    ROWP4 = (int*)carve((size_t)(NN+1)*4);
    FILL4 = (int*)carve((size_t)NN*4);
    CNT4  = (int*)carve((size_t)NN*4);
    CHUNK4= (int*)carve((size_t)NN*4);
    BSUM4 = (int*)carve(256*4);
    const int KP1 = 512;
    unsigned short* W1H  = (unsigned short*)carve((size_t)D1*KP1*2);
    unsigned short* W1L  = (unsigned short*)carve((size_t)D1*KP1*2);
    unsigned short* W4Ho = (unsigned short*)carve((size_t)D1*KP1*2);
    unsigned short* W4Lo = (unsigned short*)carve((size_t)D1*KP1*2);
    unsigned short* W10Ho= (unsigned short*)carve((size_t)D1*KP1*2);
    unsigned short* W10Lo= (unsigned short*)carve((size_t)D1*KP1*2);
    W2H  = (unsigned short*)carve((size_t)D2*KP2*2);
    W2L  = (unsigned short*)carve((size_t)D2*KP2*2);
    W5H  = (unsigned short*)carve((size_t)D2*KP2*2);
    W5L  = (unsigned short*)carve((size_t)D2*KP2*2);
    W11H = (unsigned short*)carve((size_t)D2*KP2*2);
    W11L = (unsigned short*)carve((size_t)D2*KP2*2);
    W3H  = (unsigned short*)carve((size_t)D3*KP3*2);
    W3L  = (unsigned short*)carve((size_t)D3*KP3*2);
    W6H  = (unsigned short*)carve((size_t)D3*KP3*2);
    W6L  = (unsigned short*)carve((size_t)D3*KP3*2);
    W12H = (unsigned short*)carve((size_t)D3*KP3*2);
    W12L = (unsigned short*)carve((size_t)D3*KP3*2);
    ECV4 = (int2*)carve((size_t)EE*8);
    float* fS4   = (float*)carve((size_t)NN*D1*4);
    float* fS10  = (float*)carve((size_t)NN*D1*4);
    bool fused = ((size_t)(p - (char*)d_ws) <= ws_size);
    if (!fused){ fS4 = fS1; fS10 = fS1; }

    wtc3_kernel<<<dim3(D1,3), 256, 0, stream>>>(w1, w4, w10, W1H,W1L, W4Ho,W4Lo, W10Ho,W10Lo, KF, D1, KP1);
    wtc3_kernel<<<dim3(D2,3), 256, 0, stream>>>(w2, w5, w11, W2H,W2L, W5H,W5L, W11H,W11L, D1, D2, KP2);
    wtc3_kernel<<<dim3(D3,3), 256, 0, stream>>>(w3, w6, w12, W3H,W3L, W6H,W6L, W12H,W12L, D2, D3, KP3);
    if (fused){
      mfma_gemm_kernel<128,0><<<3*NB, 256, 0, stream>>>(x, W1H,W1L, W4Ho,W4Lo, W10Ho,W10Lo,
                                                        fS1, fS4, fS10, NN, KF, KP1, 3);
    }
    auto build_csr = [&](const int* r, const int* c, const float* v){
      (void)hipMemsetAsync(CNT4, 0, (size_t)NN*4, stream);
      hist4_kernel<<<dim3((EE+255)/256,1), 256, 0, stream>>>(r, r, r, r, CNT4);
      scan1_kernel<<<dim3(NB_SCAN,1), 256, 0, stream>>>(CNT4, CHUNK4, BSUM4);
      scan2_kernel<<<1, 256, 0, stream>>>(BSUM4, NB_SCAN);
      scan3_kernel<<<dim3(NB_SCAN,1), 256, 0, stream>>>(CHUNK4, BSUM4, ROWP4, FILL4);
      scatter4_kernel<<<dim3((EE+255)/256,1), 256, 0, stream>>>(r,c,v, r,c,v, r,c,v, r,c,v, FILL4, ECV4);
    };
    auto run_branch = [&](const int* ar, const int* ac, const float* av, float* S_in,
                          const unsigned short* BhA, const unsigned short* BlA, const float* ba,
                          const unsigned short* Bh2, const unsigned short* Bl2, const float* bb,
                          const unsigned short* Bh3, const unsigned short* Bl3, const float* bc,
                          const float* dW, const float* db,
                          float* xout, float* dout, bool need_gemm1){
      build_csr(ar, ac, av);
      if (!fused && need_gemm1){
        mfma_gemm_kernel<128,0><<<NB, 256, 0, stream>>>(x, BhA,BlA, BhA,BlA, BhA,BlA,
                                                        S_in, S_in, S_in, NN, KF, KP1, 1);
      }
      spmm_kernel<128,1,float><<<(NN+3)/4, 256, 0, stream>>>(ROWP4, ECV4, S_in, ba, H1b);
      mfma_gemm_kernel<64,0><<<NB, 256, 0, stream>>>(H1b, Bh2,Bl2, Bh2,Bl2, Bh2,Bl2,
                                                     fSB, fSB, fSB, NN, D1, KP2, 1);
      spmm_kernel<64,1,float><<<(NN+3)/4, 256, 0, stream>>>(ROWP4, ECV4, fSB, bb, H2b);
      mfma_gemm_kernel<64,0><<<NB, 256, 0, stream>>>(H2b, Bh3,Bl3, Bh3,Bl3, Bh3,Bl3,
                                                     fSB, fSB, fSB, NN, D2, KP3, 1);
      spmm_kernel<64,0,float><<<(NN+3)/4, 256, 0, stream>>>(ROWP4, ECV4, fSB, bc, xout);
      dense7_kernel<<<(NN+255)/256, 256, 0, stream>>>(xout, nullptr, D3, 0, dW, db, dout, NN, 1);
    };
    run_branch(a5r, a5c, a5v, fS1,  W1H,W1L,  b1, W2H,W2L, b2, W3H,W3L, b3, d1w, d1b, XB, X1D, true);
    run_branch(a4r, a4c, a4v, fS4,  W4Ho,W4Lo, b4, W5H,W5L, b5, W6H,W6L, b6, d2w, d2b, X2, OUT_X2D, true);
    run_branch(a3r, a3c, a3v, fS4,  W4Ho,W4Lo, b4, W5H,W5L, b5, W6H,W6L, b6, d3w, d3b, X3, OUT_X3D, false);
    run_branch(a1r, a1c, a1v, fS10, W10Ho,W10Lo, b10, W11H,W11L, b11, W12H,W12L, b12, d4w, d4b, XB, X4D, true);
  }

  // sim = [x2 | x3] @ sw + sb
  dense7_kernel<<<(NN+255)/256, 256, 0, stream>>>(X2, X3, D3, D3, sw, sb, SIM, NN, 0);
  // part1 = x4d + alpha(x4d, sim)*sim
  alpha_kernel<<<1, 1024, 0, stream>>>(X4D, SIM, y, index, ALPHA);
  axpy_kernel<<<((NN*NC)+255)/256, 256, 0, stream>>>(X4D, SIM, ALPHA, OUT_P2, NN*NC);
  // part2 = part1 + alpha(part1, x1d)*x1d
  alpha_kernel<<<1, 1024, 0, stream>>>(OUT_P2, X1D, y, index, ALPHA+1);
  axpy_kernel<<<((NN*NC)+255)/256, 256, 0, stream>>>(OUT_P2, X1D, ALPHA+1, OUT_P2, NN*NC);
}

// Round 7
// 917.085 us; speedup vs baseline: 2.6299x; 1.2646x over previous
//
#include <hip/hip_runtime.h>
#include <hip/hip_fp16.h>
#include <cstddef>

#define NN 50000      // nodes
#define EE 800000     // edges per adjacency
#define KF 500        // NFEAT
#define D1 128        // H2
#define D2 64         // H3
#define D3 64         // H4
#define NC 7          // classes
#define NIDX 5000     // index size
#define NTK 16        // ceil(KF/32) k-tiles for layer-1
#define NB 391        // ceil(NN/128) row-blocks
#define NBKT 196      // ceil(NN/256) row buckets for binned scatter
#define BCHUNK 4096   // edges per bin4 block

typedef __attribute__((ext_vector_type(8))) short bf16x8;
typedef __attribute__((ext_vector_type(4))) float f32x4;
typedef __attribute__((ext_vector_type(4))) unsigned short u16x4;
typedef __attribute__((ext_vector_type(8))) unsigned short u16x8;

__device__ __forceinline__ unsigned short bfh(float f){
  unsigned u = __float_as_uint(f);
  u += 0x7FFFu + ((u >> 16) & 1u);
  return (unsigned short)(u >> 16);
}
__device__ __forceinline__ void bfsplit(float a, unsigned short& h, unsigned short& l){
  h = bfh(a);
  float r = a - __uint_as_float(((unsigned)h) << 16);
  l = bfh(r);
}

// async 1KB global->LDS stage: per-lane 16B, linear LDS dest
__device__ __forceinline__ void stage1k(const unsigned short* g, unsigned short* l, int lane){
  __builtin_amdgcn_global_load_lds((const __attribute__((address_space(1))) void*)(g + lane*8),
                                   (__attribute__((address_space(3))) void*)l, 16, 0, 0);
}

// ---------------- CSR build: hist + scan ----------------
__global__ void hist4_kernel(const int* __restrict__ r0, const int* __restrict__ r1,
                             const int* __restrict__ r2, const int* __restrict__ r3,
                             int* __restrict__ cnt4){
  int adj = blockIdx.y;
  const int* r = (adj==0)?r0:(adj==1)?r1:(adj==2)?r2:r3;
  int* cnt = cnt4 + (size_t)adj*NN;
  int i = blockIdx.x*256 + threadIdx.x;
  if (i < EE) atomicAdd(&cnt[r[i]], 1);
}
__global__ __launch_bounds__(256) void scan1_kernel(const int* __restrict__ cnt4, int* __restrict__ chunk4,
                                                    int* __restrict__ bsum4){
  int adj = blockIdx.y;
  const int* cnt = cnt4 + (size_t)adj*NN;
  int* chunk = chunk4 + (size_t)adj*NN;
  int* bsum = bsum4 + adj*256;
  __shared__ int buf[256];
  int tid = threadIdx.x;
  int i = blockIdx.x*256 + tid;
  int v = (i < NN) ? cnt[i] : 0;
  buf[tid] = v;
  __syncthreads();
  for (int off = 1; off < 256; off <<= 1){
    int t = (tid >= off) ? buf[tid - off] : 0;
    __syncthreads();
    buf[tid] += t;
    __syncthreads();
  }
  if (i < NN) chunk[i] = buf[tid] - v;
  if (tid == 255) bsum[blockIdx.x] = buf[255];
}
__global__ __launch_bounds__(256) void scan2_kernel(int* __restrict__ bsum4, int nb){
  int* bsum = bsum4 + blockIdx.x*256;
  __shared__ int buf[256];
  int tid = threadIdx.x;
  int v = (tid < nb) ? bsum[tid] : 0;
  buf[tid] = v;
  __syncthreads();
  for (int off = 1; off < 256; off <<= 1){
    int t = (tid >= off) ? buf[tid - off] : 0;
    __syncthreads();
    buf[tid] += t;
    __syncthreads();
  }
  if (tid < nb) bsum[tid] = buf[tid] - v;
}
__global__ void scan3_kernel(const int* __restrict__ chunk4, const int* __restrict__ bsum4,
                             int* __restrict__ rowp4){
  int adj = blockIdx.y;
  const int* chunk = chunk4 + (size_t)adj*NN;
  const int* bsum = bsum4 + adj*256;
  int* rowp = rowp4 + (size_t)adj*(NN+1);
  int i = blockIdx.x*256 + threadIdx.x;
  if (i < NN) rowp[i] = chunk[i] + bsum[blockIdx.x];
  if (i == 0) rowp[NN] = EE;
}
// init per-bucket global fill counters to bucket base (= rowp at bucket start)
__global__ void binit_kernel(const int* __restrict__ rowp4, int* __restrict__ gfill4){
  int adj = blockIdx.y;
  int b = threadIdx.x;
  if (b < NBKT) gfill4[adj*NBKT + b] = rowp4[(size_t)adj*(NN+1) + (b<<8)];
}

// ---------------- binned scatter pass 1: edges -> bucket-grouped intermediate ----------------
__global__ __launch_bounds__(256) void bin4_kernel(
    const int* __restrict__ r0, const int* __restrict__ c0, const float* __restrict__ v0,
    const int* __restrict__ r1, const int* __restrict__ c1, const float* __restrict__ v1,
    const int* __restrict__ r2, const int* __restrict__ c2, const float* __restrict__ v2,
    const int* __restrict__ r3, const int* __restrict__ c3, const float* __restrict__ v3,
    int* __restrict__ gfill4, int2* __restrict__ eint4){
  int adj = blockIdx.y;
  const int* r = (adj==0)?r0:(adj==1)?r1:(adj==2)?r2:r3;
  const int* c = (adj==0)?c0:(adj==1)?c1:(adj==2)?c2:c3;
  const float* v = (adj==0)?v0:(adj==1)?v1:(adj==2)?v2:v3;
  int* gf = gfill4 + adj*NBKT;
  int2* eint = eint4 + (size_t)adj*EE;
  __shared__ int cnt[256], base[256], cur[256];
  int tid = threadIdx.x;
  cnt[tid] = 0; cur[tid] = 0;
  __syncthreads();
  int e0 = blockIdx.x*BCHUNK;
  #pragma unroll
  for (int j = 0; j < BCHUNK/256; ++j){
    int i = e0 + j*256 + tid;
    if (i < EE) atomicAdd(&cnt[r[i] >> 8], 1);
  }
  __syncthreads();
  if (tid < NBKT && cnt[tid]) base[tid] = atomicAdd(&gf[tid], cnt[tid]);
  __syncthreads();
  #pragma unroll
  for (int j = 0; j < BCHUNK/256; ++j){
    int i = e0 + j*256 + tid;
    if (i < EE){
      int rr = r[i];
      int b = rr >> 8;
      int p = base[b] + atomicAdd(&cur[b], 1);
      eint[p] = make_int2((rr << 16) | c[i], __float_as_int(v[i]));
    }
  }
}
// ---------------- binned scatter pass 2: within-bucket -> final row order ----------------
__global__ __launch_bounds__(256) void order4_kernel(const int* __restrict__ rowp4,
                                                     const int2* __restrict__ eint4,
                                                     int2* __restrict__ ecv4){
  int adj = blockIdx.y;
  int b = blockIdx.x;
  const int* rowp = rowp4 + (size_t)adj*(NN+1);
  const int2* eint = eint4 + (size_t)adj*EE;
  int2* ecv = ecv4 + (size_t)adj*EE;
  int rlo = b << 8;
  int rhi = rlo + 256; if (rhi > NN) rhi = NN;
  int start = rowp[rlo], end = rowp[rhi];
  __shared__ int rcnt[256];
  rcnt[threadIdx.x] = 0;
  __syncthreads();
  for (int e = start + threadIdx.x; e < end; e += 256){
    int2 pk = eint[e];
    int rr = ((unsigned)pk.x) >> 16;
    int cc = pk.x & 0xFFFF;
    int pos = rowp[rr] + atomicAdd(&rcnt[rr - rlo], 1);
    ecv[pos] = make_int2(cc, pk.y);
  }
}

// ---------------- x -> fragment-tiled split-bf16 planes ----------------
__global__ __launch_bounds__(256) void convx_kernel(const float* __restrict__ A,
                                                    unsigned short* __restrict__ Xh,
                                                    unsigned short* __restrict__ Xl,
                                                    int M, int K){
  int rb = blockIdx.x / NTK, ks = blockIdx.x % NTK;
  __shared__ float T[128][33];
  int t = threadIdx.x;
  int tr = t >> 3, tk = (t & 7) * 4;
  #pragma unroll
  for (int p = 0; p < 4; ++p){
    int r = tr + p*32;
    int gr = rb*128 + r, gk = ks*32 + tk;
    float4 v = make_float4(0.f,0.f,0.f,0.f);
    if (gr < M && gk + 4 <= K) v = *reinterpret_cast<const float4*>(&A[(size_t)gr*K + gk]);
    T[r][tk] = v.x; T[r][tk+1] = v.y; T[r][tk+2] = v.z; T[r][tk+3] = v.w;
  }
  __syncthreads();
  size_t tb = (size_t)blockIdx.x * 4096;
  unsigned short hh[16], ll[16];
  #pragma unroll
  for (int i = 0; i < 16; ++i){
    int e = t*16 + i;
    int f = e >> 9, rem = e & 511, l = rem >> 3, kr = rem & 7;
    int row = f*16 + (l & 15), k = ((l >> 4) << 3) + kr;
    bfsplit(T[row][k], hh[i], ll[i]);
  }
  *reinterpret_cast<u16x8*>(&Xh[tb + t*16])     = *reinterpret_cast<u16x8*>(&hh[0]);
  *reinterpret_cast<u16x8*>(&Xh[tb + t*16 + 8]) = *reinterpret_cast<u16x8*>(&hh[8]);
  *reinterpret_cast<u16x8*>(&Xl[tb + t*16])     = *reinterpret_cast<u16x8*>(&ll[0]);
  *reinterpret_cast<u16x8*>(&Xl[tb + t*16 + 8]) = *reinterpret_cast<u16x8*>(&ll[8]);
}

// ---------------- big W -> fragment-tiled split planes ----------------
__global__ __launch_bounds__(256) void wtcf_kernel(const float* __restrict__ W0, const float* __restrict__ W1,
                                                   const float* __restrict__ W2,
                                                   unsigned short* __restrict__ H0, unsigned short* __restrict__ L0,
                                                   unsigned short* __restrict__ H1, unsigned short* __restrict__ L1,
                                                   unsigned short* __restrict__ H2, unsigned short* __restrict__ L2,
                                                   int K){
  int which = blockIdx.y, ks = blockIdx.x;
  const float* W = (which==0)?W0:(which==1)?W1:W2;
  unsigned short* H = (which==0)?H0:(which==1)?H1:H2;
  unsigned short* L = (which==0)?L0:(which==1)?L1:L2;
  int t = threadIdx.x;
  size_t tb = (size_t)ks * 4096;
  unsigned short hh[16], ll[16];
  #pragma unroll
  for (int i = 0; i < 16; ++i){
    int e = t*16 + i;
    int f = e >> 9, rem = e & 511, l = rem >> 3, kr = rem & 7;
    int col = f*16 + (l & 15), k = ks*32 + ((l >> 4) << 3) + kr;
    float v = (k < K) ? W[(size_t)k*D1 + col] : 0.f;
    bfsplit(v, hh[i], ll[i]);
  }
  *reinterpret_cast<u16x8*>(&H[tb + t*16])     = *reinterpret_cast<u16x8*>(&hh[0]);
  *reinterpret_cast<u16x8*>(&H[tb + t*16 + 8]) = *reinterpret_cast<u16x8*>(&hh[8]);
  *reinterpret_cast<u16x8*>(&L[tb + t*16])     = *reinterpret_cast<u16x8*>(&ll[0]);
  *reinterpret_cast<u16x8*>(&L[tb + t*16 + 8]) = *reinterpret_cast<u16x8*>(&ll[8]);
}

// ---------------- small W transpose + split: W[K][N] -> [N][Kp] planes ----------------
__global__ __launch_bounds__(256) void wtc3_kernel(
    const float* __restrict__ W0, const float* __restrict__ W1, const float* __restrict__ W2,
    unsigned short* __restrict__ H0, unsigned short* __restrict__ L0,
    unsigned short* __restrict__ H1, unsigned short* __restrict__ L1,
    unsigned short* __restrict__ H2, unsigned short* __restrict__ L2,
    int K, int N, int Kp){
  int w = blockIdx.y;
  const float* W = (w==0)?W0:(w==1)?W1:W2;
  unsigned short* H = (w==0)?H0:(w==1)?H1:H2;
  unsigned short* L = (w==0)?L0:(w==1)?L1:L2;
  int n = blockIdx.x;
  for (int k = threadIdx.x; k < Kp; k += 256){
    float v = (k < K) ? W[(size_t)k*N + n] : 0.f;
    unsigned short h, l; bfsplit(v, h, l);
    H[(size_t)n*Kp + k] = h;
    L[(size_t)n*Kp + k] = l;
  }
}

// ---------------- layer-1 fused 3x GEMM (pre-tiled, DMA staging) ----------------
__global__ __launch_bounds__(256) void gemm3f_kernel(
    const unsigned short* __restrict__ Xh, const unsigned short* __restrict__ Xl,
    const unsigned short* __restrict__ B0h, const unsigned short* __restrict__ B0l,
    const unsigned short* __restrict__ B1h, const unsigned short* __restrict__ B1l,
    const unsigned short* __restrict__ B2h, const unsigned short* __restrict__ B2l,
    __half* __restrict__ C0, __half* __restrict__ C1, __half* __restrict__ C2, int M){
  __shared__ unsigned short Ah[4096], Al[4096], Bh[4096], Bl[4096];
  int which = blockIdx.x % 3;
  int rb    = blockIdx.x / 3;
  const unsigned short* BhP = (which==0)?B0h:(which==1)?B1h:B2h;
  const unsigned short* BlP = (which==0)?B0l:(which==1)?B1l:B2l;
  __half* C = (which==0)?C0:(which==1)?C1:C2;

  int tid = threadIdx.x;
  int lane = tid & 63, wid = tid >> 6;
  int wr = wid >> 1, wc = wid & 1;

  f32x4 acc[4][4];
  #pragma unroll
  for (int i = 0; i < 4; ++i)
    #pragma unroll
    for (int j = 0; j < 4; ++j) acc[i][j] = (f32x4){0.f,0.f,0.f,0.f};

  for (int ks = 0; ks < NTK; ++ks){
    size_t atb = ((size_t)(rb*NTK + ks)) * 4096;
    size_t btb = (size_t)ks * 4096;
    const unsigned short* gsrc;
    unsigned short* ldst;
    if (wid == 0){ gsrc = Xh + atb; ldst = Ah; }
    else if (wid == 1){ gsrc = Xl + atb; ldst = Al; }
    else if (wid == 2){ gsrc = BhP + btb; ldst = Bh; }
    else { gsrc = BlP + btb; ldst = Bl; }
    #pragma unroll
    for (int c = 0; c < 8; ++c) stage1k(gsrc + c*512, ldst + c*512, lane);
    __syncthreads();

    bf16x8 ah[4], al[4], bh[4], bl[4];
    int fo = lane * 8;
    #pragma unroll
    for (int mi = 0; mi < 4; ++mi){
      ah[mi] = *reinterpret_cast<const bf16x8*>(&Ah[(wr*4 + mi)*512 + fo]);
      al[mi] = *reinterpret_cast<const bf16x8*>(&Al[(wr*4 + mi)*512 + fo]);
    }
    #pragma unroll
    for (int ni = 0; ni < 4; ++ni){
      bh[ni] = *reinterpret_cast<const bf16x8*>(&Bh[(wc*4 + ni)*512 + fo]);
      bl[ni] = *reinterpret_cast<const bf16x8*>(&Bl[(wc*4 + ni)*512 + fo]);
    }
    #pragma unroll
    for (int mi = 0; mi < 4; ++mi)
      #pragma unroll
      for (int ni = 0; ni < 4; ++ni){
        acc[mi][ni] = __builtin_amdgcn_mfma_f32_16x16x32_bf16(ah[mi], bh[ni], acc[mi][ni], 0, 0, 0);
        acc[mi][ni] = __builtin_amdgcn_mfma_f32_16x16x32_bf16(ah[mi], bl[ni], acc[mi][ni], 0, 0, 0);
        acc[mi][ni] = __builtin_amdgcn_mfma_f32_16x16x32_bf16(al[mi], bh[ni], acc[mi][ni], 0, 0, 0);
      }
    __syncthreads();
  }
  #pragma unroll
  for (int mi = 0; mi < 4; ++mi){
    int rowb = rb*128 + wr*64 + mi*16 + (lane >> 4)*4;
    #pragma unroll
    for (int ni = 0; ni < 4; ++ni){
      int col = wc*64 + ni*16 + (lane & 15);
      #pragma unroll
      for (int i = 0; i < 4; ++i){
        int r = rowb + i;
        if (r < M) C[(size_t)r*128 + col] = __float2half(acc[mi][ni][i]);
      }
    }
  }
}

// ---------------- 4-slot split-bf16 MFMA GEMM, BN=64, A fp16, C fp16 ----------------
__global__ __launch_bounds__(256) void mfma4_kernel(
    const __half* __restrict__ A0, const __half* __restrict__ A1,
    const __half* __restrict__ A2, const __half* __restrict__ A3,
    const unsigned short* __restrict__ Bh0, const unsigned short* __restrict__ Bh1,
    const unsigned short* __restrict__ Bh2, const unsigned short* __restrict__ Bh3,
    const unsigned short* __restrict__ Bl0, const unsigned short* __restrict__ Bl1,
    const unsigned short* __restrict__ Bl2, const unsigned short* __restrict__ Bl3,
    __half* __restrict__ C0, __half* __restrict__ C1,
    __half* __restrict__ C2, __half* __restrict__ C3,
    int M, int K, int Kp){
  constexpr int LD = 40;
  __shared__ __align__(16) unsigned short Ah[128*LD], Al[128*LD];
  __shared__ __align__(16) unsigned short Bhs[64*LD], Bls[64*LD];
  int slot = blockIdx.y;
  const __half* A = (slot==0)?A0:(slot==1)?A1:(slot==2)?A2:A3;
  const unsigned short* Bh = (slot==0)?Bh0:(slot==1)?Bh1:(slot==2)?Bh2:Bh3;
  const unsigned short* Bl = (slot==0)?Bl0:(slot==1)?Bl1:(slot==2)?Bl2:Bl3;
  __half* C = (slot==0)?C0:(slot==1)?C1:(slot==2)?C2:C3;

  int tid = threadIdx.x;
  int lane = tid & 63, wid = tid >> 6;
  int wr = wid >> 1, wc = wid & 1;
  int row0 = blockIdx.x*128;

  f32x4 acc[4][2];
  #pragma unroll
  for (int i = 0; i < 4; ++i){ acc[i][0] = (f32x4){0,0,0,0}; acc[i][1] = (f32x4){0,0,0,0}; }

  int sa_m = tid >> 3, sa_j = tid & 7;
  int sb_n = tid >> 2, sb_j = tid & 3;
  int fr_off = (lane & 15)*LD + (lane >> 4)*8;

  for (int k0 = 0; k0 < K; k0 += 32){
    #pragma unroll
    for (int p = 0; p < 4; ++p){
      int m = sa_m + p*32;
      int gr = row0 + m, gk = k0 + sa_j*4;
      u16x4 raw = {0,0,0,0};
      if (gr < M) raw = *reinterpret_cast<const u16x4*>(&A[(size_t)gr*K + gk]);
      unsigned short h[4], l[4];
      #pragma unroll
      for (int q = 0; q < 4; ++q){
        float f = __half2float(__ushort_as_half((unsigned short)raw[q]));
        bfsplit(f, h[q], l[q]);
      }
      u16x4 hv = {h[0],h[1],h[2],h[3]}, lv = {l[0],l[1],l[2],l[3]};
      *reinterpret_cast<u16x4*>(&Ah[m*LD + sa_j*4]) = hv;
      *reinterpret_cast<u16x4*>(&Al[m*LD + sa_j*4]) = lv;
    }
    {
      int gk = k0 + sb_j*8;
      u16x8 hv = *reinterpret_cast<const u16x8*>(&Bh[(size_t)sb_n*Kp + gk]);
      u16x8 lv = *reinterpret_cast<const u16x8*>(&Bl[(size_t)sb_n*Kp + gk]);
      *reinterpret_cast<u16x8*>(&Bhs[sb_n*LD + sb_j*8]) = hv;
      *reinterpret_cast<u16x8*>(&Bls[sb_n*LD + sb_j*8]) = lv;
    }
    __syncthreads();
    bf16x8 ah[4], al[4], bh[2], bl[2];
    #pragma unroll
    for (int mi = 0; mi < 4; ++mi){
      int off = (wr*64 + mi*16)*LD + fr_off;
      ah[mi] = *reinterpret_cast<const bf16x8*>(&Ah[off]);
      al[mi] = *reinterpret_cast<const bf16x8*>(&Al[off]);
    }
    #pragma unroll
    for (int ni = 0; ni < 2; ++ni){
      int off = (wc*32 + ni*16)*LD + fr_off;
      bh[ni] = *reinterpret_cast<const bf16x8*>(&Bhs[off]);
      bl[ni] = *reinterpret_cast<const bf16x8*>(&Bls[off]);
    }
    #pragma unroll
    for (int mi = 0; mi < 4; ++mi)
      #pragma unroll
      for (int ni = 0; ni < 2; ++ni){
        acc[mi][ni] = __builtin_amdgcn_mfma_f32_16x16x32_bf16(ah[mi], bh[ni], acc[mi][ni], 0, 0, 0);
        acc[mi][ni] = __builtin_amdgcn_mfma_f32_16x16x32_bf16(ah[mi], bl[ni], acc[mi][ni], 0, 0, 0);
        acc[mi][ni] = __builtin_amdgcn_mfma_f32_16x16x32_bf16(al[mi], bh[ni], acc[mi][ni], 0, 0, 0);
      }
    __syncthreads();
  }
  #pragma unroll
  for (int mi = 0; mi < 4; ++mi){
    int rowb = row0 + wr*64 + mi*16 + (lane >> 4)*4;
    #pragma unroll
    for (int ni = 0; ni < 2; ++ni){
      int col = wc*32 + ni*16 + (lane & 15);
      #pragma unroll
      for (int i = 0; i < 4; ++i){
        int r = rowb + i;
        if (r < M) C[(size_t)r*64 + col] = __float2half(acc[mi][ni][i]);
      }
    }
  }
}

// ---------------- 4-slot gather SpMM (fp16 S; OT = __half or float) ----------------
__device__ __forceinline__ float2 ld2f(const __half* p, int lane){
  __half2 h = ((const __half2*)p)[lane];
  return make_float2(__low2float(h), __high2float(h));
}
__device__ __forceinline__ float ld1f(const __half* p, int lane){ return __half2float(p[lane]); }
__device__ __forceinline__ void st2v(__half* p, int lane, float2 a){ ((__half2*)p)[lane] = __floats2half2_rn(a.x, a.y); }
__device__ __forceinline__ void st2v(float* p, int lane, float2 a){ ((float2*)p)[lane] = a; }
__device__ __forceinline__ void st1v(__half* p, int lane, float a){ p[lane] = __float2half(a); }
__device__ __forceinline__ void st1v(float* p, int lane, float a){ p[lane] = a; }

template<int H, int RELU, typename OT>
__global__ __launch_bounds__(256) void spmm4_kernel(
    const int* __restrict__ rp0, const int* __restrict__ rp1,
    const int* __restrict__ rp2, const int* __restrict__ rp3,
    const int2* __restrict__ e0, const int2* __restrict__ e1,
    const int2* __restrict__ e2, const int2* __restrict__ e3,
    const __half* __restrict__ S0, const __half* __restrict__ S1,
    const __half* __restrict__ S2, const __half* __restrict__ S3,
    const float* __restrict__ B0, const float* __restrict__ B1,
    const float* __restrict__ B2, const float* __restrict__ B3,
    OT* __restrict__ O0, OT* __restrict__ O1, OT* __restrict__ O2, OT* __restrict__ O3){
  int slot = blockIdx.y;
  const int* row_ptr = (slot==0)?rp0:(slot==1)?rp1:(slot==2)?rp2:rp3;
  const int2* ecv    = (slot==0)?e0:(slot==1)?e1:(slot==2)?e2:e3;
  const __half* S    = (slot==0)?S0:(slot==1)?S1:(slot==2)?S2:S3;
  const float* bias  = (slot==0)?B0:(slot==1)?B1:(slot==2)?B2:B3;
  OT* out            = (slot==0)?O0:(slot==1)?O1:(slot==2)?O2:O3;

  int row = blockIdx.x*4 + (threadIdx.x >> 6);
  int lane = threadIdx.x & 63;
  if (row >= NN) return;
  int p0 = row_ptr[row], p1 = row_ptr[row+1];
  float2 a2A = make_float2(0.f,0.f), a2B = make_float2(0.f,0.f);
  float a1A = 0.f, a1B = 0.f;
  for (int base = p0; base < p1; base += 64){
    int nrem = p1 - base; if (nrem > 64) nrem = 64;
    int2 ev = (lane < nrem) ? ecv[base + lane] : make_int2(0, 0);
    int i = 0;
    for (; i + 2 <= nrem; i += 2){
      int c0   = __shfl(ev.x, i);
      float v0 = __int_as_float(__shfl(ev.y, i));
      int c1   = __shfl(ev.x, i+1);
      float v1 = __int_as_float(__shfl(ev.y, i+1));
      if (H == 128){
        float2 s0 = ld2f(S + (size_t)c0*128, lane);
        float2 s1 = ld2f(S + (size_t)c1*128, lane);
        a2A.x += v0*s0.x; a2A.y += v0*s0.y;
        a2B.x += v1*s1.x; a2B.y += v1*s1.y;
      } else {
        a1A += v0 * ld1f(S + (size_t)c0*64, lane);
        a1B += v1 * ld1f(S + (size_t)c1*64, lane);
      }
    }
    if (i < nrem){
      int c0   = __shfl(ev.x, i);
      float v0 = __int_as_float(__shfl(ev.y, i));
      if (H == 128){
        float2 s0 = ld2f(S + (size_t)c0*128, lane);
        a2A.x += v0*s0.x; a2A.y += v0*s0.y;
      } else {
        a1A += v0 * ld1f(S + (size_t)c0*64, lane);
      }
    }
  }
  if (H == 128){
    float2 b = ((const float2*)bias)[lane];
    float2 acc = make_float2(a2A.x + a2B.x + b.x, a2A.y + a2B.y + b.y);
    if (RELU){ acc.x = fmaxf(acc.x, 0.f); acc.y = fmaxf(acc.y, 0.f); }
    st2v(out + (size_t)row*128, lane, acc);
  } else {
    float acc = a1A + a1B + bias[lane];
    if (RELU) acc = fmaxf(acc, 0.f);
    st1v(out + (size_t)row*64, lane, acc);
  }
}

// ---------------- 4-slot dense7 (K=64, relu input) ----------------
__global__ __launch_bounds__(256) void dense74_kernel(
    const float* __restrict__ A0, const float* __restrict__ A1,
    const float* __restrict__ A2, const float* __restrict__ A3,
    const float* __restrict__ W0, const float* __restrict__ W1,
    const float* __restrict__ W2, const float* __restrict__ W3,
    const float* __restrict__ bb0, const float* __restrict__ bb1,
    const float* __restrict__ bb2, const float* __restrict__ bb3,
    float* __restrict__ o0, float* __restrict__ o1,
    float* __restrict__ o2, float* __restrict__ o3){
  int slot = blockIdx.y;
  const float* A = (slot==0)?A0:(slot==1)?A1:(slot==2)?A2:A3;
  const float* W = (slot==0)?W0:(slot==1)?W1:(slot==2)?W2:W3;
  const float* bb= (slot==0)?bb0:(slot==1)?bb1:(slot==2)?bb2:bb3;
  float* o       = (slot==0)?o0:(slot==1)?o1:(slot==2)?o2:o3;
  __shared__ float Ws[64*NC];
  __shared__ float bs[NC];
  for (int i = threadIdx.x; i < 64*NC; i += 256) Ws[i] = W[i];
  if (threadIdx.x < NC) bs[threadIdx.x] = bb[threadIdx.x];
  __syncthreads();
  int row = blockIdx.x*256 + threadIdx.x;
  if (row >= NN) return;
  float acc[NC];
  #pragma unroll
  for (int n = 0; n < NC; ++n) acc[n] = bs[n];
  const float* a = A + (size_t)row*64;
  #pragma unroll 4
  for (int k = 0; k < 64; ++k){
    float av = fmaxf(a[k], 0.f);
    #pragma unroll
    for (int n = 0; n < NC; ++n) acc[n] += av*Ws[k*NC + n];
  }
  #pragma unroll
  for (int n = 0; n < NC; ++n) o[(size_t)row*NC + n] = acc[n];
}

// ---------------- sim dense: out[M,7] = [A1|A2] @ W + b ----------------
__global__ __launch_bounds__(256) void dense7_kernel(const float* __restrict__ A1, const float* __restrict__ A2,
                                                     int K1, int K2, const float* __restrict__ W,
                                                     const float* __restrict__ bias, float* __restrict__ out,
                                                     int M, int relu_in){
  __shared__ float Ws[128*NC];
  __shared__ float bs[NC];
  int K = K1 + K2;
  for (int i = threadIdx.x; i < K*NC; i += 256) Ws[i] = W[i];
  if (threadIdx.x < NC) bs[threadIdx.x] = bias[threadIdx.x];
  __syncthreads();
  int row = blockIdx.x*256 + threadIdx.x;
  if (row >= M) return;
  float acc[NC];
  #pragma unroll
  for (int n = 0; n < NC; ++n) acc[n] = bs[n];
  const float* a = A1 + (size_t)row*K1;
  for (int k = 0; k < K1; ++k){
    float av = a[k];
    if (relu_in) av = fmaxf(av, 0.f);
    #pragma unroll
    for (int n = 0; n < NC; ++n) acc[n] += av*Ws[k*NC + n];
  }
  if (A2){
    const float* a2 = A2 + (size_t)row*K2;
    for (int k = 0; k < K2; ++k){
      float av = a2[k];
      if (relu_in) av = fmaxf(av, 0.f);
      #pragma unroll
      for (int n = 0; n < NC; ++n) acc[n] += av*Ws[(K1 + k)*NC + n];
    }
  }
  #pragma unroll
  for (int n = 0; n < NC; ++n) out[(size_t)row*NC + n] = acc[n];
}

// ---------------- alpha reduction ----------------
__global__ __launch_bounds__(1024) void alpha_kernel(const float* __restrict__ base, const float* __restrict__ gate,
                                                     const float* __restrict__ y, const int* __restrict__ index,
                                                     float* __restrict__ alpha_out){
  __shared__ float r1[1024], r2[1024];
  int tid = threadIdx.x;
  float s1 = 0.f, sall = 0.f;
  for (int i = tid; i < NIDX*NC; i += 1024){
    int ii = i / NC, n = i - ii*NC;
    int r = index[ii];
    float yv = y[(size_t)r*NC + n];
    float b = base[(size_t)r*NC + n];
    float g = gate[(size_t)r*NC + n];
    float te = expf(-b*yv);
    sall += te;
    if (g*yv >= 0.f) s1 += te;
  }
  r1[tid] = s1; r2[tid] = sall;
  __syncthreads();
  for (int off = 512; off > 0; off >>= 1){
    if (tid < off){ r1[tid] += r1[tid+off]; r2[tid] += r2[tid+off]; }
    __syncthreads();
  }
  if (tid == 0){
    float s2 = r2[0] - r1[0];
    alpha_out[0] = 0.5f*logf(s2/r1[0]);
  }
}

__global__ void axpy_kernel(const float* __restrict__ a, const float* __restrict__ b,
                            const float* __restrict__ alpha, float* __restrict__ out, int n){
  int i = blockIdx.x*blockDim.x + threadIdx.x;
  if (i < n) out[i] = a[i] + alpha[0]*b[i];
}

// ---------------- host ----------------
extern "C" void kernel_launch(void* const* d_in, const int* in_sizes, int n_in,
                              void* d_out, int out_size, void* d_ws, size_t ws_size,
                              hipStream_t stream){
  const float* x     = (const float*)d_in[0];
  const float* y     = (const float*)d_in[1];
  const int*   index = (const int*)d_in[2];
  const int*   a1r = (const int*)d_in[3];  const int* a1c = (const int*)d_in[4];  const float* a1v = (const float*)d_in[5];
  const int*   a3r = (const int*)d_in[9];  const int* a3c = (const int*)d_in[10]; const float* a3v = (const float*)d_in[11];
  const int*   a4r = (const int*)d_in[12]; const int* a4c = (const int*)d_in[13]; const float* a4v = (const float*)d_in[14];
  const int*   a5r = (const int*)d_in[15]; const int* a5c = (const int*)d_in[16]; const float* a5v = (const float*)d_in[17];
  const float* w1  = (const float*)d_in[18]; const float* b1  = (const float*)d_in[19];
  const float* w2  = (const float*)d_in[20]; const float* b2  = (const float*)d_in[21];
  const float* w3  = (const float*)d_in[22]; const float* b3  = (const float*)d_in[23];
  const float* w4  = (const float*)d_in[24]; const float* b4  = (const float*)d_in[25];
  const float* w5  = (const float*)d_in[26]; const float* b5  = (const float*)d_in[27];
  const float* w6  = (const float*)d_in[28]; const float* b6  = (const float*)d_in[29];
  const float* w10 = (const float*)d_in[30]; const float* b10 = (const float*)d_in[31];
  const float* w11 = (const float*)d_in[32]; const float* b11 = (const float*)d_in[33];
  const float* w12 = (const float*)d_in[34]; const float* b12 = (const float*)d_in[35];
  const float* d1w = (const float*)d_in[36]; const float* d1b = (const float*)d_in[37];
  const float* d2w = (const float*)d_in[38]; const float* d2b = (const float*)d_in[39];
  const float* d3w = (const float*)d_in[40]; const float* d3b = (const float*)d_in[41];
  const float* d4w = (const float*)d_in[42]; const float* d4b = (const float*)d_in[43];
  const float* sw  = (const float*)d_in[44]; const float* sb  = (const float*)d_in[45];
  float* out = (float*)d_out;
  (void)n_in; (void)in_sizes; (void)out_size; (void)ws_size;

  float* OUT_X2D = out;
  float* OUT_X3D = out + (size_t)NN*NC;
  float* OUT_P2  = out + (size_t)2*NN*NC;

  char* p = (char*)d_ws;
  auto carve = [&](size_t bytes) -> char* {
    char* q = p;
    p += (bytes + 255) & ~size_t(255);
    return q;
  };

  // Region A (102.5MB), time-shared:
  //   phase 1: EINT (bucket-grouped edges, 25.6MB)     [CSR build]
  //   phase 2: Xh | Xl fragment-tiled planes           [convx .. gemm3f]
  //   phase 3: H1_4 (51.2) | SB_4 (25.6) | H2_4 (25.6) [branch stages]
  const size_t XH_BYTES = (size_t)NB*NTK*4096*2;     // 51,249,152
  char* regionA = carve(2*XH_BYTES);
  unsigned short* Xh = (unsigned short*)regionA;
  unsigned short* Xl = (unsigned short*)(regionA + XH_BYTES);
  int2*   EINT4 = (int2*)regionA;                     // 25.6MB <= 51.2
  __half* H1_4  = (__half*)regionA;                   // 4*NN*128*2 = 51.2MB
  __half* SB_4  = (__half*)(regionA + XH_BYTES);                 // 25.6MB
  __half* H2_4  = (__half*)(regionA + XH_BYTES + (size_t)4*NN*D2*2); // 25.6MB

  __half* S1  = (__half*)carve((size_t)NN*D1*2);
  __half* S4  = (__half*)carve((size_t)NN*D1*2);
  __half* S10 = (__half*)carve((size_t)NN*D1*2);
  float* X1R  = (float*)carve((size_t)NN*D3*4);
  float* X2   = (float*)carve((size_t)NN*D3*4);
  float* X3   = (float*)carve((size_t)NN*D3*4);
  float* X4R  = (float*)carve((size_t)NN*D3*4);
  float* X1D  = (float*)carve((size_t)NN*NC*4);
  float* X4D  = (float*)carve((size_t)NN*NC*4);
  float* SIM  = (float*)carve((size_t)NN*NC*4);
  float* ALPHA= (float*)carve(256);
  int*   ROWP4 = (int*)carve((size_t)4*(NN+1)*4);
  int*   CNT4  = (int*)carve((size_t)4*NN*4);
  int*   CHUNK4= (int*)carve((size_t)4*NN*4);
  int*   BSUM4 = (int*)carve(4*256*4);
  int*   GFILL4= (int*)carve(4*NBKT*4);
  const size_t BTE = (size_t)NTK*4096;
  unsigned short* B1H = (unsigned short*)carve(BTE*2); unsigned short* B1L = (unsigned short*)carve(BTE*2);
  unsigned short* B4H = (unsigned short*)carve(BTE*2); unsigned short* B4L = (unsigned short*)carve(BTE*2);
  unsigned short* B10H= (unsigned short*)carve(BTE*2); unsigned short* B10L= (unsigned short*)carve(BTE*2);
  const int KP2 = 128, KP3 = 64;
  unsigned short* W2H  = (unsigned short*)carve((size_t)D2*KP2*2);
  unsigned short* W2L  = (unsigned short*)carve((size_t)D2*KP2*2);
  unsigned short* W5H  = (unsigned short*)carve((size_t)D2*KP2*2);
  unsigned short* W5L  = (unsigned short*)carve((size_t)D2*KP2*2);
  unsigned short* W11H = (unsigned short*)carve((size_t)D2*KP2*2);
  unsigned short* W11L = (unsigned short*)carve((size_t)D2*KP2*2);
  unsigned short* W3H  = (unsigned short*)carve((size_t)D3*KP3*2);
  unsigned short* W3L  = (unsigned short*)carve((size_t)D3*KP3*2);
  unsigned short* W6H  = (unsigned short*)carve((size_t)D3*KP3*2);
  unsigned short* W6L  = (unsigned short*)carve((size_t)D3*KP3*2);
  unsigned short* W12H = (unsigned short*)carve((size_t)D3*KP3*2);
  unsigned short* W12L = (unsigned short*)carve((size_t)D3*KP3*2);
  int2*  ECV4 = (int2*)carve((size_t)4*EE*8);
  // total ~225MB; round-6 path used ~258MB of d_ws successfully, so this fits.

  const int NB_SCAN = (NN + 255)/256;   // 196
  const int NCHUNK  = (EE + BCHUNK - 1)/BCHUNK;

  int* rp0 = ROWP4;                       // slot 0 = x1 (a5)
  int* rp1 = ROWP4 + (size_t)(NN+1);      // slot 1 = x2 (a4)
  int* rp2 = ROWP4 + (size_t)2*(NN+1);    // slot 2 = x3 (a3)
  int* rp3 = ROWP4 + (size_t)3*(NN+1);    // slot 3 = x4 (a1)
  int2* ec0 = ECV4;
  int2* ec1 = ECV4 + (size_t)EE;
  int2* ec2 = ECV4 + (size_t)2*EE;
  int2* ec3 = ECV4 + (size_t)3*EE;
  __half* H1s0 = H1_4;                    __half* H1s1 = H1_4 + (size_t)NN*D1;
  __half* H1s2 = H1_4 + (size_t)2*NN*D1;  __half* H1s3 = H1_4 + (size_t)3*NN*D1;
  __half* SBs0 = SB_4;                    __half* SBs1 = SB_4 + (size_t)NN*D2;
  __half* SBs2 = SB_4 + (size_t)2*NN*D2;  __half* SBs3 = SB_4 + (size_t)3*NN*D2;
  __half* H2s0 = H2_4;                    __half* H2s1 = H2_4 + (size_t)NN*D2;
  __half* H2s2 = H2_4 + (size_t)2*NN*D2;  __half* H2s3 = H2_4 + (size_t)3*NN*D2;

  // ---- 1. CSR build (all 4 adjacencies), binned scatter; uses regionA as EINT ----
  (void)hipMemsetAsync(CNT4, 0, (size_t)4*NN*4, stream);
  hist4_kernel<<<dim3((EE+255)/256,4), 256, 0, stream>>>(a5r, a4r, a3r, a1r, CNT4);
  scan1_kernel<<<dim3(NB_SCAN,4), 256, 0, stream>>>(CNT4, CHUNK4, BSUM4);
  scan2_kernel<<<4, 256, 0, stream>>>(BSUM4, NB_SCAN);
  scan3_kernel<<<dim3(NB_SCAN,4), 256, 0, stream>>>(CHUNK4, BSUM4, ROWP4);
  binit_kernel<<<dim3(1,4), 256, 0, stream>>>(ROWP4, GFILL4);
  bin4_kernel<<<dim3(NCHUNK,4), 256, 0, stream>>>(a5r,a5c,a5v, a4r,a4c,a4v, a3r,a3c,a3v, a1r,a1c,a1v,
                                                  GFILL4, EINT4);
  order4_kernel<<<dim3(NBKT,4), 256, 0, stream>>>(ROWP4, EINT4, ECV4);

  // ---- 2. feature/weight prep (regionA becomes Xh/Xl) ----
  convx_kernel<<<NB*NTK, 256, 0, stream>>>(x, Xh, Xl, NN, KF);
  wtcf_kernel<<<dim3(NTK,3), 256, 0, stream>>>(w1, w4, w10, B1H,B1L, B4H,B4L, B10H,B10L, KF);
  wtc3_kernel<<<dim3(D2,3), 256, 0, stream>>>(w2, w5, w11, W2H,W2L, W5H,W5L, W11H,W11L, D1, D2, KP2);
  wtc3_kernel<<<dim3(D3,3), 256, 0, stream>>>(w3, w6, w12, W3H,W3L, W6H,W6L, W12H,W12L, D2, D3, KP3);

  // ---- 3. fused layer-1 GEMMs: S = x @ {w1,w4,w10} (fp16 out) ----
  gemm3f_kernel<<<3*NB, 256, 0, stream>>>(Xh, Xl, B1H,B1L, B4H,B4L, B10H,B10L, S1, S4, S10, NN);

  // ---- 4. branch stages, 4-way fused (slots: x1/a5, x2/a4, x3/a3, x4/a1) ----
  // regionA becomes H1_4 | SB_4 | H2_4 (Xh/Xl dead after gemm3f)
  spmm4_kernel<128,1,__half><<<dim3((NN+3)/4,4), 256, 0, stream>>>(
      rp0,rp1,rp2,rp3, ec0,ec1,ec2,ec3, S1,S4,S4,S10, b1,b4,b4,b10,
      H1s0,H1s1,H1s2,H1s3);
  mfma4_kernel<<<dim3(NB,4), 256, 0, stream>>>(
      H1s0,H1s1,H1s2,H1s3, W2H,W5H,W5H,W11H, W2L,W5L,W5L,W11L,
      SBs0,SBs1,SBs2,SBs3, NN, D1, KP2);
  spmm4_kernel<64,1,__half><<<dim3((NN+3)/4,4), 256, 0, stream>>>(
      rp0,rp1,rp2,rp3, ec0,ec1,ec2,ec3, SBs0,SBs1,SBs2,SBs3, b2,b5,b5,b11,
      H2s0,H2s1,H2s2,H2s3);
  mfma4_kernel<<<dim3(NB,4), 256, 0, stream>>>(
      H2s0,H2s1,H2s2,H2s3, W3H,W6H,W6H,W12H, W3L,W6L,W6L,W12L,
      SBs0,SBs1,SBs2,SBs3, NN, D2, KP3);
  spmm4_kernel<64,0,float><<<dim3((NN+3)/4,4), 256, 0, stream>>>(
      rp0,rp1,rp2,rp3, ec0,ec1,ec2,ec3, SBs0,SBs1,SBs2,SBs3, b3,b6,b6,b12,
      X1R,X2,X3,X4R);
  dense74_kernel<<<dim3((NN+255)/256,4), 256, 0, stream>>>(
      X1R,X2,X3,X4R, d1w,d2w,d3w,d4w, d1b,d2b,d3b,d4b,
      X1D, OUT_X2D, OUT_X3D, X4D);

  // ---- 5. sim + adaboost epilogue ----
  dense7_kernel<<<(NN+255)/256, 256, 0, stream>>>(X2, X3, D3, D3, sw, sb, SIM, NN, 0);
  alpha_kernel<<<1, 1024, 0, stream>>>(X4D, SIM, y, index, ALPHA);
  axpy_kernel<<<((NN*NC)+255)/256, 256, 0, stream>>>(X4D, SIM, ALPHA, OUT_P2, NN*NC);
  alpha_kernel<<<1, 1024, 0, stream>>>(OUT_P2, X1D, y, index, ALPHA+1);
  axpy_kernel<<<((NN*NC)+255)/256, 256, 0, stream>>>(OUT_P2, X1D, ALPHA+1, OUT_P2, NN*NC);
}